// Round 1
// baseline (6913.430 us; speedup 1.0000x reference)
//
#include <hip/hip_runtime.h>
#include <math.h>

#define BATCH  2
#define CCH    128      // residual channels C
#define CCH2   256      // 2C
#define CINC   80       // conditioning channels
#define HH     16
#define WW     4096
#define HW     (HH*WW)
#define NLAYER 8
#define TW     64       // pixels per block tile
#define KC     8        // K chunk

// sizes (floats)
#define H_ELEMS   (BATCH*CCH*HW)       // 16777216
#define FGWT_N    (NLAYER*9*CCH*CCH2)  // 2359296
#define FGCT_N    (NLAYER*CINC*CCH2)   // 163840
#define RST_N     (NLAYER*CCH*CCH2)    // 262144

__device__ __forceinline__ float sigm(float x) { return 1.0f / (1.0f + __expf(-x)); }

// ---------------- weight transpose: [o][ci][kh][kw] -> [tap][ci][o] ----------------
__global__ void transpose_weights(const float* __restrict__ fg_w,
                                  const float* __restrict__ fgc_w,
                                  const float* __restrict__ rs_w,
                                  float* __restrict__ fgwT,
                                  float* __restrict__ fgcT,
                                  float* __restrict__ rsT) {
    const int n1 = FGWT_N;            // fg:  (((i*256+o)*128+ci)*3+kh)*3+kw
    const int n2 = FGCT_N;            // fgc: (i*256+o)*80+ci
    const int n3 = RST_N;             // rs:  (i*256+o)*128+ci
    int stride = gridDim.x * blockDim.x;
    for (int idx = blockIdx.x * blockDim.x + threadIdx.x; idx < n1 + n2 + n3; idx += stride) {
        if (idx < n1) {
            int t = idx;
            int kw = t % 3; t /= 3;
            int kh = t % 3; t /= 3;
            int ci = t % CCH; t /= CCH;
            int o  = t % CCH2;
            int i  = t / CCH2;
            fgwT[((i*9 + kh*3 + kw)*CCH + ci)*CCH2 + o] = fg_w[idx];
        } else if (idx < n1 + n2) {
            int t = idx - n1;
            int ci = t % CINC; t /= CINC;
            int o  = t % CCH2;
            int i  = t / CCH2;
            fgcT[(i*CINC + ci)*CCH2 + o] = fgc_w[idx - n1];
        } else {
            int t = idx - n1 - n2;
            int ci = t % CCH; t /= CCH;
            int o  = t % CCH2;
            int i  = t / CCH2;
            rsT[(i*CCH + ci)*CCH2 + o] = rs_w[idx - n1 - n2];
        }
    }
}

// ---------------- front 1x1 conv + zero skip ----------------
__global__ void front_kernel(const float* __restrict__ x,
                             const float* __restrict__ fw,
                             const float* __restrict__ fb,
                             float* __restrict__ h,
                             float* __restrict__ skip) {
    int stride = gridDim.x * blockDim.x;
    for (int idx = blockIdx.x * blockDim.x + threadIdx.x; idx < H_ELEMS; idx += stride) {
        int yx = idx % HW;
        int cc = (idx / HW) % CCH;
        int b  = idx / (CCH * HW);
        h[idx]    = fw[cc] * x[b*HW + yx] + fb[cc];
        skip[idx] = 0.0f;
    }
}

// ---------------- per-layer gate kernel: a = dilated3x3(h) + 1x1(c); acts = tanh*sig ----------------
// block: 256 threads; tile: 256 out-ch x 64 px of one (b,y) row.
// thread: og = tid>>3 (0..31), pxl = tid&7. Owns out rows {og*4+m} (filter) and
// {128+og*4+m} (gate), px = pxl*8 + p (p 0..7).
__global__ __launch_bounds__(256) void gate_kernel(
        const float* __restrict__ h, const float* __restrict__ cin,
        const float* __restrict__ fgwT, const float* __restrict__ fgcT,
        const float* __restrict__ fg_b, const float* __restrict__ fgc_b,
        float* __restrict__ acts, int layer, int dh, int dw) {
    __shared__ float Wl[KC][CCH2];
    __shared__ float Xl[KC][TW];

    const int tid = threadIdx.x;
    const int og  = tid >> 3;
    const int pxl = tid & 7;
    const int bx  = blockIdx.x & 63;   // W/TW == 64
    const int row = blockIdx.x >> 6;   // 0..31
    const int y   = row & 15;
    const int b   = row >> 4;
    const int x0  = bx * TW;

    float accF[4][8], accG[4][8];
#pragma unroll
    for (int m = 0; m < 4; ++m)
#pragma unroll
        for (int p = 0; p < 8; ++p) { accF[m][p] = 0.f; accG[m][p] = 0.f; }

    const float* wl_base = fgwT + (size_t)layer * 9 * CCH * CCH2;

    // ---- 9 dilated taps ----
    for (int kh = 0; kh < 3; ++kh) {
        int yin = y - (2 - kh) * dh;
        if (yin < 0) continue;
        for (int kw = 0; kw < 3; ++kw) {
            int xoff = (kw - 1) * dw;
            const float* wt = wl_base + (kh*3 + kw) * CCH * CCH2;
            const float* hb = h + ((size_t)(b*CCH) * HH + yin) * WW; // + ci*HW + x
            for (int c0 = 0; c0 < CCH; c0 += KC) {
                __syncthreads();
#pragma unroll
                for (int j = 0; j < KC; ++j)
                    Wl[j][tid] = wt[(c0 + j)*CCH2 + tid];
#pragma unroll
                for (int j = 0; j < 2; ++j) {
                    int k  = (tid >> 6) + 4*j;
                    int px = tid & 63;
                    int xin = x0 + px + xoff;
                    Xl[k][px] = (xin >= 0 && xin < WW) ? hb[(size_t)(c0 + k)*HW + xin] : 0.f;
                }
                __syncthreads();
#pragma unroll
                for (int k = 0; k < KC; ++k) {
                    float xv[8], wf[4], wg[4];
                    *(float4*)&xv[0] = *(const float4*)&Xl[k][pxl*8];
                    *(float4*)&xv[4] = *(const float4*)&Xl[k][pxl*8 + 4];
                    *(float4*)&wf[0] = *(const float4*)&Wl[k][og*4];
                    *(float4*)&wg[0] = *(const float4*)&Wl[k][128 + og*4];
#pragma unroll
                    for (int m = 0; m < 4; ++m)
#pragma unroll
                        for (int p = 0; p < 8; ++p) {
                            accF[m][p] += wf[m] * xv[p];
                            accG[m][p] += wg[m] * xv[p];
                        }
                }
            }
        }
    }

    // ---- conditioning 1x1 over 80 channels ----
    {
        const float* wc = fgcT + (size_t)layer * CINC * CCH2;
        const float* cb = cin + ((size_t)(b*CINC) * HH + y) * WW;
        for (int c0 = 0; c0 < CINC; c0 += KC) {
            __syncthreads();
#pragma unroll
            for (int j = 0; j < KC; ++j)
                Wl[j][tid] = wc[(c0 + j)*CCH2 + tid];
#pragma unroll
            for (int j = 0; j < 2; ++j) {
                int k  = (tid >> 6) + 4*j;
                int px = tid & 63;
                Xl[k][px] = cb[(size_t)(c0 + k)*HW + x0 + px];
            }
            __syncthreads();
#pragma unroll
            for (int k = 0; k < KC; ++k) {
                float xv[8], wf[4], wg[4];
                *(float4*)&xv[0] = *(const float4*)&Xl[k][pxl*8];
                *(float4*)&xv[4] = *(const float4*)&Xl[k][pxl*8 + 4];
                *(float4*)&wf[0] = *(const float4*)&Wl[k][og*4];
                *(float4*)&wg[0] = *(const float4*)&Wl[k][128 + og*4];
#pragma unroll
                for (int m = 0; m < 4; ++m)
#pragma unroll
                    for (int p = 0; p < 8; ++p) {
                        accF[m][p] += wf[m] * xv[p];
                        accG[m][p] += wg[m] * xv[p];
                    }
            }
        }
    }

    // ---- bias + gated activation -> acts [B][128][H][W] ----
    const float* bf  = fg_b  + layer * CCH2;
    const float* bc2 = fgc_b + layer * CCH2;
#pragma unroll
    for (int m = 0; m < 4; ++m) {
        int of  = og*4 + m;
        int ogg = 128 + of;
        float bF = bf[of]  + bc2[of];
        float bG = bf[ogg] + bc2[ogg];
        float* arow = acts + ((size_t)(b*CCH + of) * HH + y) * WW + x0 + pxl*8;
        float out[8];
#pragma unroll
        for (int p = 0; p < 8; ++p) {
            float aF = accF[m][p] + bF;
            float aG = accG[m][p] + bG;
            out[p] = tanhf(aF) * sigm(aG);
        }
        *(float4*)&arow[0] = *(float4*)&out[0];
        *(float4*)&arow[4] = *(float4*)&out[4];
    }
}

// ---------------- per-layer res/skip kernel: rs = 1x1(acts); h += rs[:128]; skip += rs[128:] ----------------
__global__ __launch_bounds__(256) void resskip_kernel(
        const float* __restrict__ acts, const float* __restrict__ rsT,
        const float* __restrict__ rs_b,
        float* __restrict__ h, float* __restrict__ skip, int layer) {
    __shared__ float Wl[KC][CCH2];
    __shared__ float Xl[KC][TW];

    const int tid = threadIdx.x;
    const int og  = tid >> 3;
    const int pxl = tid & 7;
    const int bx  = blockIdx.x & 63;
    const int row = blockIdx.x >> 6;
    const int y   = row & 15;
    const int b   = row >> 4;
    const int x0  = bx * TW;

    float accF[4][8], accG[4][8];
#pragma unroll
    for (int m = 0; m < 4; ++m)
#pragma unroll
        for (int p = 0; p < 8; ++p) { accF[m][p] = 0.f; accG[m][p] = 0.f; }

    const float* wt = rsT + (size_t)layer * CCH * CCH2;
    const float* ab = acts + ((size_t)(b*CCH) * HH + y) * WW;

    for (int c0 = 0; c0 < CCH; c0 += KC) {
        __syncthreads();
#pragma unroll
        for (int j = 0; j < KC; ++j)
            Wl[j][tid] = wt[(c0 + j)*CCH2 + tid];
#pragma unroll
        for (int j = 0; j < 2; ++j) {
            int k  = (tid >> 6) + 4*j;
            int px = tid & 63;
            Xl[k][px] = ab[(size_t)(c0 + k)*HW + x0 + px];
        }
        __syncthreads();
#pragma unroll
        for (int k = 0; k < KC; ++k) {
            float xv[8], wf[4], wg[4];
            *(float4*)&xv[0] = *(const float4*)&Xl[k][pxl*8];
            *(float4*)&xv[4] = *(const float4*)&Xl[k][pxl*8 + 4];
            *(float4*)&wf[0] = *(const float4*)&Wl[k][og*4];
            *(float4*)&wg[0] = *(const float4*)&Wl[k][128 + og*4];
#pragma unroll
            for (int m = 0; m < 4; ++m)
#pragma unroll
                for (int p = 0; p < 8; ++p) {
                    accF[m][p] += wf[m] * xv[p];
                    accG[m][p] += wg[m] * xv[p];
                }
        }
    }

    const float* rb = rs_b + layer * CCH2;
#pragma unroll
    for (int m = 0; m < 4; ++m) {
        int of  = og*4 + m;
        int ogg = 128 + of;
        float bF = rb[of];
        float bG = rb[ogg];
        float* hrow = h    + ((size_t)(b*CCH + of) * HH + y) * WW + x0 + pxl*8;
        float* srow = skip + ((size_t)(b*CCH + of) * HH + y) * WW + x0 + pxl*8;
        float4 hv0 = *(float4*)&hrow[0];
        float4 hv1 = *(float4*)&hrow[4];
        float4 sv0 = *(float4*)&srow[0];
        float4 sv1 = *(float4*)&srow[4];
        hv0.x += accF[m][0] + bF; hv0.y += accF[m][1] + bF;
        hv0.z += accF[m][2] + bF; hv0.w += accF[m][3] + bF;
        hv1.x += accF[m][4] + bF; hv1.y += accF[m][5] + bF;
        hv1.z += accF[m][6] + bF; hv1.w += accF[m][7] + bF;
        sv0.x += accG[m][0] + bG; sv0.y += accG[m][1] + bG;
        sv0.z += accG[m][2] + bG; sv0.w += accG[m][3] + bG;
        sv1.x += accG[m][4] + bG; sv1.y += accG[m][5] + bG;
        sv1.z += accG[m][6] + bG; sv1.w += accG[m][7] + bG;
        *(float4*)&hrow[0] = hv0; *(float4*)&hrow[4] = hv1;
        *(float4*)&srow[0] = sv0; *(float4*)&srow[4] = sv1;
    }
}

extern "C" void kernel_launch(void* const* d_in, const int* in_sizes, int n_in,
                              void* d_out, int out_size, void* d_ws, size_t ws_size,
                              hipStream_t stream) {
    const float* x       = (const float*)d_in[0];
    const float* c       = (const float*)d_in[1];
    const float* front_w = (const float*)d_in[2];
    const float* front_b = (const float*)d_in[3];
    const float* fg_w    = (const float*)d_in[4];
    const float* fg_b    = (const float*)d_in[5];
    const float* fgc_w   = (const float*)d_in[6];
    const float* fgc_b   = (const float*)d_in[7];
    const float* rs_w    = (const float*)d_in[8];
    const float* rs_b    = (const float*)d_in[9];

    float* skip = (float*)d_out;
    float* ws   = (float*)d_ws;
    float* h    = ws;                     // H_ELEMS
    float* acts = h + H_ELEMS;            // H_ELEMS
    float* fgwT = acts + H_ELEMS;         // FGWT_N
    float* fgcT = fgwT + FGWT_N;          // FGCT_N
    float* rsT  = fgcT + FGCT_N;          // RST_N

    transpose_weights<<<2048, 256, 0, stream>>>(fg_w, fgc_w, rs_w, fgwT, fgcT, rsT);
    front_kernel<<<2048, 256, 0, stream>>>(x, front_w, front_b, h, skip);

    static const int DILH[NLAYER] = {1, 2, 4, 8, 1, 2, 4, 8};
    static const int DILW[NLAYER] = {1, 2, 4, 8, 16, 32, 64, 128};

    const int nblk = BATCH * HH * (WW / TW); // 2048
    for (int i = 0; i < NLAYER; ++i) {
        gate_kernel<<<nblk, 256, 0, stream>>>(h, c, fgwT, fgcT, fg_b, fgc_b,
                                              acts, i, DILH[i], DILW[i]);
        resskip_kernel<<<nblk, 256, 0, stream>>>(acts, rsT, rs_b, h, skip, i);
    }
}

// Round 2
// 2594.255 us; speedup vs baseline: 2.6649x; 2.6649x over previous
//
#include <hip/hip_runtime.h>
#include <math.h>

#define NL    8
#define CCH   128
#define CINC  80
#define CPAD  96
#define HH    16
#define WW    4096
#define HW    (HH*WW)
#define PADW  128
#define WWP   (WW + 2*PADW)
#define NQ    39            // 9 taps * 4 kchunks + 3 cond kchunks

// workspace element counts
#define HF32_N  (2*HW*CCH)            // 16777216 f32
#define SKIP_N  (2*HW*CCH)            // 16777216 f32
#define HBF_N   (2*HH*WWP*CCH)        // 17825792 u16
#define ACTS_N  (2*HW*CCH)            // 16777216 u16
#define CT_N    (2*HW*CPAD)           // 12582912 u16
#define GW_N    (NL*NQ*16*64*8)       // 2555904 u16
#define RW_N    (NL*4*16*64*8)        // 262144 u16

using v8s  = __attribute__((ext_vector_type(8))) short;
using f32x4 = __attribute__((ext_vector_type(4))) float;

__device__ __forceinline__ unsigned short f2bf(float f) {
    unsigned int u = __builtin_bit_cast(unsigned int, f);
    u += 0x7fffu + ((u >> 16) & 1u);
    return (unsigned short)(u >> 16);
}
__device__ __forceinline__ float sigm(float x) { return 1.0f / (1.0f + __expf(-x)); }

// ---------- one-time weight swizzle into MFMA A-fragment order ----------
// gw[i][tq][mt][lane][j]: A[m = mt*16 + (lane&15)][k = q*32 + 8*(lane>>4) + j]
// out-channel permutation: gemm row m -> original o = (m&1)*128 + (m>>1)
__global__ void prep_weights(const float* __restrict__ fg_w, const float* __restrict__ fgc_w,
                             const float* __restrict__ rs_w,
                             const float* __restrict__ fg_b, const float* __restrict__ fgc_b,
                             const float* __restrict__ rs_b,
                             unsigned short* __restrict__ gw, unsigned short* __restrict__ rw,
                             float* __restrict__ gbias, float* __restrict__ rbias) {
    const int total = GW_N + RW_N + 2 * NL * 256;
    const int stride = gridDim.x * blockDim.x;
    for (int idx = blockIdx.x * blockDim.x + threadIdx.x; idx < total; idx += stride) {
        if (idx < GW_N) {
            int t = idx;
            int j = t & 7;  t >>= 3;
            int l = t & 63; t >>= 6;
            int mt = t & 15; t >>= 4;
            int tq = t % NQ;
            int i  = t / NQ;
            int m  = mt*16 + (l & 15);
            int oo = (m & 1)*128 + (m >> 1);
            int cio = 8*(l >> 4) + j;
            float v;
            if (tq < 36) {
                int tt = tq >> 2, q = tq & 3;
                int ci = q*32 + cio;
                v = fg_w[(((size_t)i*256 + oo)*128 + ci)*9 + tt];
            } else {
                int q = tq - 36;
                int ci = q*32 + cio;
                v = (ci < CINC) ? fgc_w[((size_t)i*256 + oo)*CINC + ci] : 0.0f;
            }
            gw[idx] = f2bf(v);
        } else if (idx < GW_N + RW_N) {
            int t = idx - GW_N;
            int j = t & 7;  t >>= 3;
            int l = t & 63; t >>= 6;
            int mt = t & 15; t >>= 4;
            int q = t & 3;
            int i = t >> 2;
            int m  = mt*16 + (l & 15);
            int oo = (m & 1)*128 + (m >> 1);
            int ci = q*32 + 8*(l >> 4) + j;
            rw[idx - GW_N] = f2bf(rs_w[((size_t)i*256 + oo)*128 + ci]);
        } else {
            int t = idx - GW_N - RW_N;
            if (t < NL*256) {
                int i = t >> 8, m = t & 255;
                int oo = (m & 1)*128 + (m >> 1);
                gbias[t] = fg_b[i*256 + oo] + fgc_b[i*256 + oo];
            } else {
                t -= NL*256;
                int i = t >> 8, m = t & 255;
                int oo = (m & 1)*128 + (m >> 1);
                rbias[t] = rs_b[i*256 + oo];
            }
        }
    }
}

// ---------- front 1x1 conv: h (fp32 + padded bf16), zero skip ----------
__global__ void front_kernel(const float* __restrict__ xsrc,
                             const float* __restrict__ fw, const float* __restrict__ fb,
                             float* __restrict__ hf32, unsigned short* __restrict__ hbf,
                             float* __restrict__ skipws) {
    const int stride = gridDim.x * blockDim.x;
    for (int idx = blockIdx.x * blockDim.x + threadIdx.x; idx < HBF_N; idx += stride) {
        int c = idx & 127;
        int rest = idx >> 7;
        int xp = rest % WWP; rest /= WWP;
        int y = rest & 15;
        int b = rest >> 4;
        int x = xp - PADW;
        if (x >= 0 && x < WW) {
            float v = fw[c] * xsrc[((size_t)(b*HH + y))*WW + x] + fb[c];
            hbf[idx] = f2bf(v);
            size_t io = (((size_t)(b*HH + y))*WW + x)*CCH + c;
            hf32[io] = v;
            skipws[io] = 0.0f;
        } else {
            hbf[idx] = 0;
        }
    }
}

// ---------- conditioning transpose: c [b][80][y][x] f32 -> cT [b][y][x][96] bf16 ----------
__global__ __launch_bounds__(256) void cond_transpose(const float* __restrict__ cin,
                                                      unsigned short* __restrict__ cT) {
    __shared__ unsigned short lt[CINC][72];
    const int tid = threadIdx.x, lane = tid & 63, w = tid >> 6;
    const int x0 = blockIdx.x * 64, y = blockIdx.y, b = blockIdx.z;
#pragma unroll
    for (int r = 0; r < 20; ++r) {
        int ci = w*20 + r;
        float v = cin[(((size_t)(b*CINC + ci))*HH + y)*WW + x0 + lane];
        lt[ci][lane] = f2bf(v);
    }
    __syncthreads();
    const int px = tid & 63, cg = tid >> 6;
    unsigned int pk[12];
#pragma unroll
    for (int kk = 0; kk < 12; ++kk) {
        int c0 = cg*24 + kk*2;
        unsigned int lo = (c0     < CINC) ? lt[c0][px]     : 0;
        unsigned int hi = (c0 + 1 < CINC) ? lt[c0 + 1][px] : 0;
        pk[kk] = lo | (hi << 16);
    }
    unsigned short* dst = cT + (((size_t)(b*HH + y))*WW + x0 + px)*CPAD + cg*24;
    *(uint4*)(dst)     = make_uint4(pk[0], pk[1], pk[2], pk[3]);
    *(uint4*)(dst + 8) = make_uint4(pk[4], pk[5], pk[6], pk[7]);
    *(uint4*)(dst + 16)= make_uint4(pk[8], pk[9], pk[10], pk[11]);
}

// ---------- gate: a = dilated3x3(h) + 1x1(c); acts = tanh * sigmoid ----------
// block = 4 waves; tile 256(m, permuted) x 64(px). wave w: m in [w*64, w*64+64).
__global__ __launch_bounds__(256) void gate_mfma(
        const unsigned short* __restrict__ hbf, const unsigned short* __restrict__ cT,
        const unsigned short* __restrict__ gw, const float* __restrict__ gbias,
        unsigned short* __restrict__ acts, int layer, int dh, int dw) {
    const int tid = threadIdx.x, lane = tid & 63, w = tid >> 6;
    const int lrow = lane & 15, lk = lane >> 4;
    const int x0 = blockIdx.x * 64, y = blockIdx.y, b = blockIdx.z;

    f32x4 acc[4][4];
#pragma unroll
    for (int mf = 0; mf < 4; ++mf)
#pragma unroll
        for (int nf = 0; nf < 4; ++nf) acc[mf][nf] = (f32x4){0.f, 0.f, 0.f, 0.f};

    const unsigned short* gwp = gw + (((size_t)layer*NQ)*16 + w*4)*512 + lane*8;

    for (int tq = 0; tq < NQ; ++tq, gwp += 16*512) {
        const unsigned short* src;
        int spix;
        if (tq < 36) {
            int tt = tq >> 2, q = tq & 3;
            int kh = tt / 3, kw = tt % 3;
            int yin = y - (2 - kh)*dh;
            if (yin < 0) continue;
            src = hbf + (((size_t)(b*HH + yin))*WWP + x0 + (kw - 1)*dw + PADW)*CCH + q*32 + lk*8;
            spix = CCH;
        } else {
            int q = tq - 36;
            src = cT + (((size_t)(b*HH + y))*WW + x0)*CPAD + q*32 + lk*8;
            spix = CPAD;
        }
        v8s av[4], bv[4];
#pragma unroll
        for (int mf = 0; mf < 4; ++mf) av[mf] = *(const v8s*)(gwp + mf*512);
#pragma unroll
        for (int nf = 0; nf < 4; ++nf) bv[nf] = *(const v8s*)(src + (size_t)(nf*16 + lrow)*spix);
#pragma unroll
        for (int mf = 0; mf < 4; ++mf)
#pragma unroll
            for (int nf = 0; nf < 4; ++nf)
                acc[mf][nf] = __builtin_amdgcn_mfma_f32_16x16x32_bf16(av[mf], bv[nf], acc[mf][nf], 0, 0, 0);
    }

    const float* gb = gbias + layer*256;
#pragma unroll
    for (int mf = 0; mf < 4; ++mf) {
        int m0 = w*64 + mf*16 + lk*4;
        int c0 = m0 >> 1;
        float bF0 = gb[m0], bG0 = gb[m0+1], bF1 = gb[m0+2], bG1 = gb[m0+3];
#pragma unroll
        for (int nf = 0; nf < 4; ++nf) {
            int px = x0 + nf*16 + lrow;
            float o0 = tanhf(acc[mf][nf][0] + bF0) * sigm(acc[mf][nf][1] + bG0);
            float o1 = tanhf(acc[mf][nf][2] + bF1) * sigm(acc[mf][nf][3] + bG1);
            unsigned int pk = (unsigned int)f2bf(o0) | ((unsigned int)f2bf(o1) << 16);
            *(unsigned int*)(acts + (((size_t)(b*HH + y))*WW + px)*CCH + c0) = pk;
        }
    }
}

// ---------- res/skip: rs = 1x1(acts); h += rs[:128] (fp32 + bf16 shadow); skip += rs[128:] ----------
__global__ __launch_bounds__(256) void resskip_mfma(
        const unsigned short* __restrict__ acts, const unsigned short* __restrict__ rw,
        const float* __restrict__ rbias,
        float* __restrict__ hf32, unsigned short* __restrict__ hbf,
        float* __restrict__ skipws, int layer) {
    const int tid = threadIdx.x, lane = tid & 63, w = tid >> 6;
    const int lrow = lane & 15, lk = lane >> 4;
    const int x0 = blockIdx.x * 64, y = blockIdx.y, b = blockIdx.z;

    f32x4 acc[4][4];
#pragma unroll
    for (int mf = 0; mf < 4; ++mf)
#pragma unroll
        for (int nf = 0; nf < 4; ++nf) acc[mf][nf] = (f32x4){0.f, 0.f, 0.f, 0.f};

    const unsigned short* rwp = rw + (((size_t)layer*4)*16 + w*4)*512 + lane*8;
    const unsigned short* srcb = acts + (((size_t)(b*HH + y))*WW + x0)*CCH + lk*8;

    for (int q = 0; q < 4; ++q, rwp += 16*512) {
        const unsigned short* src = srcb + q*32;
        v8s av[4], bv[4];
#pragma unroll
        for (int mf = 0; mf < 4; ++mf) av[mf] = *(const v8s*)(rwp + mf*512);
#pragma unroll
        for (int nf = 0; nf < 4; ++nf) bv[nf] = *(const v8s*)(src + (size_t)(nf*16 + lrow)*CCH);
#pragma unroll
        for (int mf = 0; mf < 4; ++mf)
#pragma unroll
            for (int nf = 0; nf < 4; ++nf)
                acc[mf][nf] = __builtin_amdgcn_mfma_f32_16x16x32_bf16(av[mf], bv[nf], acc[mf][nf], 0, 0, 0);
    }

    const float* rb = rbias + layer*256;
#pragma unroll
    for (int mf = 0; mf < 4; ++mf) {
        int m0 = w*64 + mf*16 + lk*4;
        int c0 = m0 >> 1;
        float bR0 = rb[m0], bS0 = rb[m0+1], bR1 = rb[m0+2], bS1 = rb[m0+3];
#pragma unroll
        for (int nf = 0; nf < 4; ++nf) {
            int px = x0 + nf*16 + lrow;
            size_t io = (((size_t)(b*HH + y))*WW + px)*CCH + c0;
            float2 hv = *(float2*)(hf32 + io);
            hv.x += acc[mf][nf][0] + bR0;
            hv.y += acc[mf][nf][2] + bR1;
            *(float2*)(hf32 + io) = hv;
            unsigned int pk = (unsigned int)f2bf(hv.x) | ((unsigned int)f2bf(hv.y) << 16);
            *(unsigned int*)(hbf + (((size_t)(b*HH + y))*WWP + px + PADW)*CCH + c0) = pk;
            float2 sv = *(float2*)(skipws + io);
            sv.x += acc[mf][nf][1] + bS0;
            sv.y += acc[mf][nf][3] + bS1;
            *(float2*)(skipws + io) = sv;
        }
    }
}

// ---------- final transpose: skipws [b][y][x][c] -> d_out [b][c][y][x] ----------
__global__ __launch_bounds__(256) void final_transpose(const float* __restrict__ skipws,
                                                       float* __restrict__ out) {
    __shared__ float t[64][129];
    const int tid = threadIdx.x;
    const int x0 = blockIdx.x * 64, y = blockIdx.y, b = blockIdx.z;
    {
        int px = tid >> 2, cq = tid & 3;
        const float* src = skipws + (((size_t)(b*HH + y))*WW + x0 + px)*CCH + cq*32;
#pragma unroll
        for (int i = 0; i < 8; ++i) {
            float4 v = *(const float4*)(src + i*4);
            t[px][cq*32 + i*4 + 0] = v.x;
            t[px][cq*32 + i*4 + 1] = v.y;
            t[px][cq*32 + i*4 + 2] = v.z;
            t[px][cq*32 + i*4 + 3] = v.w;
        }
    }
    __syncthreads();
    {
        int c = tid >> 1, xh = tid & 1;
        float* dst = out + (((size_t)(b*CCH + c))*HH + y)*WW + x0 + xh*32;
#pragma unroll
        for (int i = 0; i < 8; ++i) {
            float4 v;
            v.x = t[xh*32 + i*4 + 0][c];
            v.y = t[xh*32 + i*4 + 1][c];
            v.z = t[xh*32 + i*4 + 2][c];
            v.w = t[xh*32 + i*4 + 3][c];
            *(float4*)(dst + i*4) = v;
        }
    }
}

extern "C" void kernel_launch(void* const* d_in, const int* in_sizes, int n_in,
                              void* d_out, int out_size, void* d_ws, size_t ws_size,
                              hipStream_t stream) {
    const float* x       = (const float*)d_in[0];
    const float* c       = (const float*)d_in[1];
    const float* front_w = (const float*)d_in[2];
    const float* front_b = (const float*)d_in[3];
    const float* fg_w    = (const float*)d_in[4];
    const float* fg_b    = (const float*)d_in[5];
    const float* fgc_w   = (const float*)d_in[6];
    const float* fgc_b   = (const float*)d_in[7];
    const float* rs_w    = (const float*)d_in[8];
    const float* rs_b    = (const float*)d_in[9];

    char* ws = (char*)d_ws;
    float* hf32   = (float*)ws;                       ws += (size_t)HF32_N * 4;
    float* skipws = (float*)ws;                       ws += (size_t)SKIP_N * 4;
    unsigned short* hbf  = (unsigned short*)ws;       ws += (size_t)HBF_N * 2;
    unsigned short* acts = (unsigned short*)ws;       ws += (size_t)ACTS_N * 2;
    unsigned short* cT   = (unsigned short*)ws;       ws += (size_t)CT_N * 2;
    unsigned short* gw   = (unsigned short*)ws;       ws += (size_t)GW_N * 2;
    unsigned short* rwq  = (unsigned short*)ws;       ws += (size_t)RW_N * 2;
    float* gbias  = (float*)ws;                       ws += (size_t)NL * 256 * 4;
    float* rbias  = (float*)ws;

    prep_weights<<<2048, 256, 0, stream>>>(fg_w, fgc_w, rs_w, fg_b, fgc_b, rs_b,
                                           gw, rwq, gbias, rbias);
    front_kernel<<<2048, 256, 0, stream>>>(x, front_w, front_b, hf32, hbf, skipws);
    cond_transpose<<<dim3(64, 16, 2), 256, 0, stream>>>(c, cT);

    static const int DILH[NL] = {1, 2, 4, 8, 1, 2, 4, 8};
    static const int DILW[NL] = {1, 2, 4, 8, 16, 32, 64, 128};

    for (int i = 0; i < NL; ++i) {
        gate_mfma<<<dim3(64, 16, 2), 256, 0, stream>>>(hbf, cT, gw, gbias, acts, i, DILH[i], DILW[i]);
        resskip_mfma<<<dim3(64, 16, 2), 256, 0, stream>>>(acts, rwq, rbias, hf32, hbf, skipws, i);
    }
    final_transpose<<<dim3(64, 16, 2), 256, 0, stream>>>(skipws, (float*)d_out);
}

// Round 3
// 2162.094 us; speedup vs baseline: 3.1976x; 1.1999x over previous
//
#include <hip/hip_runtime.h>
#include <math.h>

#define NL    8
#define CCH   128
#define CINC  80
#define CPAD  96
#define HH    16
#define WW    4096
#define HW    (HH*WW)
#define PADW  128
#define WWP   (WW + 2*PADW)
#define NQ    39            // 9 taps * 4 kchunks + 3 cond kchunks

// workspace element counts
#define HF32_N  (2*HW*CCH)            // f32
#define SKIP_N  (2*HW*CCH)            // f32
#define HBF_N   (2*HH*WWP*CCH)        // u16 (per buffer)
#define ZROW_N  (WWP*CCH)             // u16
#define CT_N    (2*HW*CPAD)           // u16
#define GW_N    (NL*NQ*16*64*8)       // u16
#define RW_N    (NL*4*16*64*8)        // u16

using v8s   = __attribute__((ext_vector_type(8))) short;
using f32x4 = __attribute__((ext_vector_type(4))) float;

__device__ __forceinline__ unsigned short f2bf(float f) {
    unsigned int u = __builtin_bit_cast(unsigned int, f);
    u += 0x7fffu + ((u >> 16) & 1u);
    return (unsigned short)(u >> 16);
}
__device__ __forceinline__ float sigm(float x) { return 1.0f / (1.0f + __expf(-x)); }

// ---------- one-time weight swizzle into MFMA A-fragment order ----------
// gw[i][tq][mt][lane][j]: A[m = mt*16 + (lane&15)][k = q*32 + 8*(lane>>4) + j]
// out-channel permutation: gemm row m -> original o = (m&1)*128 + (m>>1)
__global__ void prep_weights(const float* __restrict__ fg_w, const float* __restrict__ fgc_w,
                             const float* __restrict__ rs_w,
                             const float* __restrict__ fg_b, const float* __restrict__ fgc_b,
                             const float* __restrict__ rs_b,
                             unsigned short* __restrict__ gw, unsigned short* __restrict__ rw,
                             float* __restrict__ gbias, float* __restrict__ rbias) {
    const int total = GW_N + RW_N + 2 * NL * 256;
    const int stride = gridDim.x * blockDim.x;
    for (int idx = blockIdx.x * blockDim.x + threadIdx.x; idx < total; idx += stride) {
        if (idx < GW_N) {
            int t = idx;
            int j = t & 7;  t >>= 3;
            int l = t & 63; t >>= 6;
            int mt = t & 15; t >>= 4;
            int tq = t % NQ;
            int i  = t / NQ;
            int m  = mt*16 + (l & 15);
            int oo = (m & 1)*128 + (m >> 1);
            int cio = 8*(l >> 4) + j;
            float v;
            if (tq < 36) {
                int tt = tq >> 2, q = tq & 3;
                int ci = q*32 + cio;
                v = fg_w[(((size_t)i*256 + oo)*128 + ci)*9 + tt];
            } else {
                int q = tq - 36;
                int ci = q*32 + cio;
                v = (ci < CINC) ? fgc_w[((size_t)i*256 + oo)*CINC + ci] : 0.0f;
            }
            gw[idx] = f2bf(v);
        } else if (idx < GW_N + RW_N) {
            int t = idx - GW_N;
            int j = t & 7;  t >>= 3;
            int l = t & 63; t >>= 6;
            int mt = t & 15; t >>= 4;
            int q = t & 3;
            int i = t >> 2;
            int m  = mt*16 + (l & 15);
            int oo = (m & 1)*128 + (m >> 1);
            int ci = q*32 + 8*(l >> 4) + j;
            rw[idx - GW_N] = f2bf(rs_w[((size_t)i*256 + oo)*128 + ci]);
        } else {
            int t = idx - GW_N - RW_N;
            if (t < NL*256) {
                int i = t >> 8, m = t & 255;
                int oo = (m & 1)*128 + (m >> 1);
                gbias[t] = fg_b[i*256 + oo] + fgc_b[i*256 + oo];
            } else {
                t -= NL*256;
                int i = t >> 8, m = t & 255;
                int oo = (m & 1)*128 + (m >> 1);
                rbias[t] = rs_b[i*256 + oo];
            }
        }
    }
}

// ---------- front 1x1 conv: h (fp32 + padded bf16 buf0), zero buf1/zrow/skip ----------
__global__ void front_kernel(const float* __restrict__ xsrc,
                             const float* __restrict__ fw, const float* __restrict__ fb,
                             float* __restrict__ hf32, unsigned short* __restrict__ hbf0,
                             unsigned short* __restrict__ hbf1, unsigned short* __restrict__ zrow,
                             float* __restrict__ skipws) {
    const int stride = gridDim.x * blockDim.x;
    const int t0 = blockIdx.x * blockDim.x + threadIdx.x;
    for (int idx = t0; idx < HBF_N; idx += stride) {
        int c = idx & 127;
        int rest = idx >> 7;
        int xp = rest % WWP; rest /= WWP;
        int y = rest & 15;
        int b = rest >> 4;
        int x = xp - PADW;
        if (x >= 0 && x < WW) {
            float v = fw[c] * xsrc[((size_t)(b*HH + y))*WW + x] + fb[c];
            hbf0[idx] = f2bf(v);
            size_t io = (((size_t)(b*HH + y))*WW + x)*CCH + c;
            hf32[io] = v;
            skipws[io] = 0.0f;
        } else {
            hbf0[idx] = 0;
        }
    }
    for (int idx = t0; idx < HBF_N; idx += stride) hbf1[idx] = 0;
    for (int idx = t0; idx < ZROW_N; idx += stride) zrow[idx] = 0;
}

// ---------- conditioning transpose: c [b][80][y][x] f32 -> cT [b][y][x][96] bf16 ----------
__global__ __launch_bounds__(256) void cond_transpose(const float* __restrict__ cin,
                                                      unsigned short* __restrict__ cT) {
    __shared__ unsigned short lt[CINC][72];
    const int tid = threadIdx.x, lane = tid & 63, w = tid >> 6;
    const int x0 = blockIdx.x * 64, y = blockIdx.y, b = blockIdx.z;
#pragma unroll
    for (int r = 0; r < 20; ++r) {
        int ci = w*20 + r;
        float v = cin[(((size_t)(b*CINC + ci))*HH + y)*WW + x0 + lane];
        lt[ci][lane] = f2bf(v);
    }
    __syncthreads();
    const int px = tid & 63, cg = tid >> 6;
    unsigned int pk[12];
#pragma unroll
    for (int kk = 0; kk < 12; ++kk) {
        int c0 = cg*24 + kk*2;
        unsigned int lo = (c0     < CINC) ? lt[c0][px]     : 0;
        unsigned int hi = (c0 + 1 < CINC) ? lt[c0 + 1][px] : 0;
        pk[kk] = lo | (hi << 16);
    }
    unsigned short* dst = cT + (((size_t)(b*HH + y))*WW + x0 + px)*CPAD + cg*24;
    *(uint4*)(dst)      = make_uint4(pk[0], pk[1], pk[2], pk[3]);
    *(uint4*)(dst + 8)  = make_uint4(pk[4], pk[5], pk[6], pk[7]);
    *(uint4*)(dst + 16) = make_uint4(pk[8], pk[9], pk[10], pk[11]);
}

// ---------- fused layer: gate (dilated 3x3 + cond 1x1, tanh*sig) + res/skip 1x1 ----------
// block = 4 waves; tile 256(m, permuted) x 64(px). wave w owns m in [w*64, w*64+64).
__global__ __launch_bounds__(256) void layer_fused(
        const unsigned short* __restrict__ hin, unsigned short* __restrict__ hout,
        const unsigned short* __restrict__ zrow, const unsigned short* __restrict__ cT,
        const unsigned short* __restrict__ gw, const float* __restrict__ gbias,
        const unsigned short* __restrict__ rw, const float* __restrict__ rbias,
        float* __restrict__ hf32, float* __restrict__ skipws,
        int layer, int dh, int dw) {
    __shared__ unsigned short sact[64 * CCH];   // 16 KB, XOR-swizzled [px][c]

    const int tid = threadIdx.x, lane = tid & 63, w = tid >> 6;
    const int lrow = lane & 15, lk = lane >> 4;
    const int x0 = blockIdx.x * 64, y = blockIdx.y, b = blockIdx.z;

    f32x4 acc[4][4];
#pragma unroll
    for (int mf = 0; mf < 4; ++mf)
#pragma unroll
        for (int nf = 0; nf < 4; ++nf) acc[mf][nf] = (f32x4){0.f, 0.f, 0.f, 0.f};

    const unsigned short* gwl = gw + (((size_t)layer*NQ*16) + w*4)*512 + lane*8;

    // fragment loader: branch-free over taps (yin<0 -> shared zero row)
    auto loadf = [&](int tq, v8s (&av)[4], v8s (&bv)[4]) {
        const unsigned short* sp; int stq;
        if (tq < 36) {
            int tt = tq >> 2, q = tq & 3;
            int kh = tt / 3, kw = tt - kh*3;
            int yin = y - (2 - kh)*dh;
            const unsigned short* base = (yin >= 0)
                ? hin + ((size_t)(b*HH + yin))*WWP*CCH
                : zrow;
            sp = base + (size_t)(x0 + (kw - 1)*dw + PADW)*CCH + q*32 + lk*8;
            stq = CCH;
        } else {
            int q = tq - 36;
            sp = cT + (((size_t)(b*HH + y))*WW + x0)*CPAD + q*32 + lk*8;
            stq = CPAD;
        }
        const unsigned short* gp = gwl + (size_t)tq*16*512;
#pragma unroll
        for (int mf = 0; mf < 4; ++mf) av[mf] = *(const v8s*)(gp + mf*512);
#pragma unroll
        for (int nf = 0; nf < 4; ++nf) bv[nf] = *(const v8s*)(sp + (size_t)(nf*16 + lrow)*stq);
    };
    auto mf16 = [&](v8s (&av)[4], v8s (&bv)[4]) {
#pragma unroll
        for (int mf = 0; mf < 4; ++mf)
#pragma unroll
            for (int nf = 0; nf < 4; ++nf)
                acc[mf][nf] = __builtin_amdgcn_mfma_f32_16x16x32_bf16(av[mf], bv[nf], acc[mf][nf], 0, 0, 0);
    };

    // 2-deep software pipeline over NQ=39 uniform k-steps
    v8s avA[4], bvA[4], avB[4], bvB[4];
    loadf(0, avA, bvA);
    for (int t = 0; t < 37; t += 2) {
        loadf(t + 1, avB, bvB);
        mf16(avA, bvA);
        loadf(t + 2, avA, bvA);
        mf16(avB, bvB);
    }
    mf16(avA, bvA);   // tq = 38

    // ---- gated activation -> LDS (bf16, XOR-swizzled) ----
    const float* gb = gbias + layer*256;
#pragma unroll
    for (int mf = 0; mf < 4; ++mf) {
        int m0 = w*64 + mf*16 + lk*4;
        int c0 = m0 >> 1;                     // even
        float bF0 = gb[m0], bG0 = gb[m0+1], bF1 = gb[m0+2], bG1 = gb[m0+3];
#pragma unroll
        for (int nf = 0; nf < 4; ++nf) {
            int px = nf*16 + lrow;
            float o0 = tanhf(acc[mf][nf][0] + bF0) * sigm(acc[mf][nf][1] + bG0);
            float o1 = tanhf(acc[mf][nf][2] + bF1) * sigm(acc[mf][nf][3] + bG1);
            unsigned int pk = (unsigned int)f2bf(o0) | ((unsigned int)f2bf(o1) << 16);
            int byte = px*256 + c0*2;
            byte ^= (px & 7) << 4;
            *(unsigned int*)((char*)sact + byte) = pk;
        }
    }
    __syncthreads();

    // ---- res/skip 1x1 GEMM from LDS ----
    f32x4 racc[4][4];
#pragma unroll
    for (int mf = 0; mf < 4; ++mf)
#pragma unroll
        for (int nf = 0; nf < 4; ++nf) racc[mf][nf] = (f32x4){0.f, 0.f, 0.f, 0.f};

    const unsigned short* rwl = rw + (((size_t)layer*4*16) + w*4)*512 + lane*8;
#pragma unroll
    for (int q = 0; q < 4; ++q) {
        v8s av[4], bv[4];
#pragma unroll
        for (int mf = 0; mf < 4; ++mf) av[mf] = *(const v8s*)(rwl + (size_t)(q*16 + mf)*512);
#pragma unroll
        for (int nf = 0; nf < 4; ++nf) {
            int px = nf*16 + lrow;
            int byte = px*256 + q*64 + lk*16;
            byte ^= (px & 7) << 4;
            bv[nf] = *(const v8s*)((char*)sact + byte);
        }
#pragma unroll
        for (int mf = 0; mf < 4; ++mf)
#pragma unroll
            for (int nf = 0; nf < 4; ++nf)
                racc[mf][nf] = __builtin_amdgcn_mfma_f32_16x16x32_bf16(av[mf], bv[nf], racc[mf][nf], 0, 0, 0);
    }

    // ---- h += rs[:128] (fp32 + bf16 shadow into hout); skip += rs[128:] ----
    const float* rb = rbias + layer*256;
#pragma unroll
    for (int mf = 0; mf < 4; ++mf) {
        int m0 = w*64 + mf*16 + lk*4;
        int c0 = m0 >> 1;
        float bR0 = rb[m0], bS0 = rb[m0+1], bR1 = rb[m0+2], bS1 = rb[m0+3];
#pragma unroll
        for (int nf = 0; nf < 4; ++nf) {
            int px = x0 + nf*16 + lrow;
            size_t io = (((size_t)(b*HH + y))*WW + px)*CCH + c0;
            float2 hv = *(float2*)(hf32 + io);
            hv.x += racc[mf][nf][0] + bR0;
            hv.y += racc[mf][nf][2] + bR1;
            *(float2*)(hf32 + io) = hv;
            unsigned int pk = (unsigned int)f2bf(hv.x) | ((unsigned int)f2bf(hv.y) << 16);
            *(unsigned int*)(hout + (((size_t)(b*HH + y))*WWP + px + PADW)*CCH + c0) = pk;
            float2 sv = *(float2*)(skipws + io);
            sv.x += racc[mf][nf][1] + bS0;
            sv.y += racc[mf][nf][3] + bS1;
            *(float2*)(skipws + io) = sv;
        }
    }
}

// ---------- final transpose: skipws [b][y][x][c] -> d_out [b][c][y][x] ----------
__global__ __launch_bounds__(256) void final_transpose(const float* __restrict__ skipws,
                                                       float* __restrict__ out) {
    __shared__ float t[64][129];
    const int tid = threadIdx.x;
    const int x0 = blockIdx.x * 64, y = blockIdx.y, b = blockIdx.z;
    {
        int px = tid >> 2, cq = tid & 3;
        const float* src = skipws + (((size_t)(b*HH + y))*WW + x0 + px)*CCH + cq*32;
#pragma unroll
        for (int i = 0; i < 8; ++i) {
            float4 v = *(const float4*)(src + i*4);
            t[px][cq*32 + i*4 + 0] = v.x;
            t[px][cq*32 + i*4 + 1] = v.y;
            t[px][cq*32 + i*4 + 2] = v.z;
            t[px][cq*32 + i*4 + 3] = v.w;
        }
    }
    __syncthreads();
    {
        int c = tid >> 1, xh = tid & 1;
        float* dst = out + (((size_t)(b*CCH + c))*HH + y)*WW + x0 + xh*32;
#pragma unroll
        for (int i = 0; i < 8; ++i) {
            float4 v;
            v.x = t[xh*32 + i*4 + 0][c];
            v.y = t[xh*32 + i*4 + 1][c];
            v.z = t[xh*32 + i*4 + 2][c];
            v.w = t[xh*32 + i*4 + 3][c];
            *(float4*)(dst + i*4) = v;
        }
    }
}

extern "C" void kernel_launch(void* const* d_in, const int* in_sizes, int n_in,
                              void* d_out, int out_size, void* d_ws, size_t ws_size,
                              hipStream_t stream) {
    const float* x       = (const float*)d_in[0];
    const float* c       = (const float*)d_in[1];
    const float* front_w = (const float*)d_in[2];
    const float* front_b = (const float*)d_in[3];
    const float* fg_w    = (const float*)d_in[4];
    const float* fg_b    = (const float*)d_in[5];
    const float* fgc_w   = (const float*)d_in[6];
    const float* fgc_b   = (const float*)d_in[7];
    const float* rs_w    = (const float*)d_in[8];
    const float* rs_b    = (const float*)d_in[9];

    char* ws = (char*)d_ws;
    float* hf32   = (float*)ws;                     ws += (size_t)HF32_N * 4;
    float* skipws = (float*)ws;                     ws += (size_t)SKIP_N * 4;
    unsigned short* hbf0 = (unsigned short*)ws;     ws += (size_t)HBF_N * 2;
    unsigned short* hbf1 = (unsigned short*)ws;     ws += (size_t)HBF_N * 2;
    unsigned short* zrow = (unsigned short*)ws;     ws += (size_t)ZROW_N * 2;
    unsigned short* cT   = (unsigned short*)ws;     ws += (size_t)CT_N * 2;
    unsigned short* gw   = (unsigned short*)ws;     ws += (size_t)GW_N * 2;
    unsigned short* rwq  = (unsigned short*)ws;     ws += (size_t)RW_N * 2;
    float* gbias  = (float*)ws;                     ws += (size_t)NL * 256 * 4;
    float* rbias  = (float*)ws;

    prep_weights<<<2048, 256, 0, stream>>>(fg_w, fgc_w, rs_w, fg_b, fgc_b, rs_b,
                                           gw, rwq, gbias, rbias);
    front_kernel<<<2048, 256, 0, stream>>>(x, front_w, front_b, hf32, hbf0, hbf1, zrow, skipws);
    cond_transpose<<<dim3(64, 16, 2), 256, 0, stream>>>(c, cT);

    static const int DILH[NL] = {1, 2, 4, 8, 1, 2, 4, 8};
    static const int DILW[NL] = {1, 2, 4, 8, 16, 32, 64, 128};

    for (int i = 0; i < NL; ++i) {
        const unsigned short* hin = (i & 1) ? hbf1 : hbf0;
        unsigned short*       hout= (i & 1) ? hbf0 : hbf1;
        layer_fused<<<dim3(64, 16, 2), 256, 0, stream>>>(hin, hout, zrow, cT, gw, gbias,
                                                         rwq, rbias, hf32, skipws,
                                                         i, DILH[i], DILW[i]);
    }
    final_transpose<<<dim3(64, 16, 2), 256, 0, stream>>>(skipws, (float*)d_out);
}

// Round 4
// 2134.802 us; speedup vs baseline: 3.2384x; 1.0128x over previous
//
#include <hip/hip_runtime.h>
#include <math.h>

#define NL    8
#define CCH   128
#define CINC  80
#define CPAD  96
#define HH    16
#define WW    4096
#define HW    (HH*WW)
#define PADW  128
#define WWP   (WW + 2*PADW)
#define NQ    39            // 9 taps * 4 kchunks + 3 cond kchunks

// workspace element counts
#define HF32_N  (2*HW*CCH)            // f32
#define HBF_N   (2*HH*WWP*CCH)        // u16 (per buffer)
#define ZROW_N  (WWP*CCH)             // u16
#define CT_N    (2*HW*CPAD)           // u16
#define GW_N    (NL*NQ*16*64*8)       // u16
#define RW_N    (NL*4*16*64*8)        // u16

using v8s   = __attribute__((ext_vector_type(8))) short;
using f32x4 = __attribute__((ext_vector_type(4))) float;

__device__ __forceinline__ unsigned short f2bf(float f) {
    unsigned int u = __builtin_bit_cast(unsigned int, f);
    u += 0x7fffu + ((u >> 16) & 1u);
    return (unsigned short)(u >> 16);
}
__device__ __forceinline__ float sigm(float x) { return 1.0f / (1.0f + __expf(-x)); }

// ---------- one-time weight swizzle into MFMA A-fragment order ----------
// gw[i][tq][mt][lane][j]: A[m = mt*16 + (lane&15)][k = q*32 + 8*(lane>>4) + j]
// out-channel permutation: gemm row m -> original o = (m&1)*128 + (m>>1)
__global__ void prep_weights(const float* __restrict__ fg_w, const float* __restrict__ fgc_w,
                             const float* __restrict__ rs_w,
                             const float* __restrict__ fg_b, const float* __restrict__ fgc_b,
                             const float* __restrict__ rs_b,
                             unsigned short* __restrict__ gw, unsigned short* __restrict__ rw,
                             float* __restrict__ gbias, float* __restrict__ rbias) {
    const int total = GW_N + RW_N + 2 * NL * 256;
    const int stride = gridDim.x * blockDim.x;
    for (int idx = blockIdx.x * blockDim.x + threadIdx.x; idx < total; idx += stride) {
        if (idx < GW_N) {
            int t = idx;
            int j = t & 7;  t >>= 3;
            int l = t & 63; t >>= 6;
            int mt = t & 15; t >>= 4;
            int tq = t % NQ;
            int i  = t / NQ;
            int m  = mt*16 + (l & 15);
            int oo = (m & 1)*128 + (m >> 1);
            int cio = 8*(l >> 4) + j;
            float v;
            if (tq < 36) {
                int tt = tq >> 2, q = tq & 3;
                int ci = q*32 + cio;
                v = fg_w[(((size_t)i*256 + oo)*128 + ci)*9 + tt];
            } else {
                int q = tq - 36;
                int ci = q*32 + cio;
                v = (ci < CINC) ? fgc_w[((size_t)i*256 + oo)*CINC + ci] : 0.0f;
            }
            gw[idx] = f2bf(v);
        } else if (idx < GW_N + RW_N) {
            int t = idx - GW_N;
            int j = t & 7;  t >>= 3;
            int l = t & 63; t >>= 6;
            int mt = t & 15; t >>= 4;
            int q = t & 3;
            int i = t >> 2;
            int m  = mt*16 + (l & 15);
            int oo = (m & 1)*128 + (m >> 1);
            int ci = q*32 + 8*(l >> 4) + j;
            rw[idx - GW_N] = f2bf(rs_w[((size_t)i*256 + oo)*128 + ci]);
        } else {
            int t = idx - GW_N - RW_N;
            if (t < NL*256) {
                int i = t >> 8, m = t & 255;
                int oo = (m & 1)*128 + (m >> 1);
                gbias[t] = fg_b[i*256 + oo] + fgc_b[i*256 + oo];
            } else {
                t -= NL*256;
                int i = t >> 8, m = t & 255;
                int oo = (m & 1)*128 + (m >> 1);
                rbias[t] = rs_b[i*256 + oo];
            }
        }
    }
}

// ---------- front 1x1 conv: hf32 (plane-major) + padded bf16 buf0; zero buf1/zrow/out ----------
__global__ void front_kernel(const float* __restrict__ xsrc,
                             const float* __restrict__ fw, const float* __restrict__ fb,
                             float* __restrict__ hf32, unsigned short* __restrict__ hbf0,
                             unsigned short* __restrict__ hbf1, unsigned short* __restrict__ zrow,
                             float* __restrict__ outskip) {
    const int stride = gridDim.x * blockDim.x;
    const int t0 = blockIdx.x * blockDim.x + threadIdx.x;
    for (int idx = t0; idx < HBF_N; idx += stride) {
        int c = idx & 127;
        int rest = idx >> 7;
        int xp = rest % WWP; rest /= WWP;
        int y = rest & 15;
        int b = rest >> 4;
        int x = xp - PADW;
        if (x >= 0 && x < WW) {
            float v = fw[c] * xsrc[((size_t)(b*HH + y))*WW + x] + fb[c];
            hbf0[idx] = f2bf(v);
            hf32[(((size_t)(b*CCH + c))*HH + y)*WW + x] = v;
        } else {
            hbf0[idx] = 0;
        }
    }
    for (int idx = t0; idx < HBF_N; idx += stride) hbf1[idx] = 0;
    for (int idx = t0; idx < ZROW_N; idx += stride) zrow[idx] = 0;
    for (int idx = t0; idx < HF32_N; idx += stride) outskip[idx] = 0.0f;
}

// ---------- conditioning transpose: c [b][80][y][x] f32 -> cT [b][y][x][96] bf16 ----------
__global__ __launch_bounds__(256) void cond_transpose(const float* __restrict__ cin,
                                                      unsigned short* __restrict__ cT) {
    __shared__ unsigned short lt[CINC][72];
    const int tid = threadIdx.x, lane = tid & 63, w = tid >> 6;
    const int x0 = blockIdx.x * 64, y = blockIdx.y, b = blockIdx.z;
#pragma unroll
    for (int r = 0; r < 20; ++r) {
        int ci = w*20 + r;
        float v = cin[(((size_t)(b*CINC + ci))*HH + y)*WW + x0 + lane];
        lt[ci][lane] = f2bf(v);
    }
    __syncthreads();
    const int px = tid & 63, cg = tid >> 6;
    unsigned int pk[12];
#pragma unroll
    for (int kk = 0; kk < 12; ++kk) {
        int c0 = cg*24 + kk*2;
        unsigned int lo = (c0     < CINC) ? lt[c0][px]     : 0;
        unsigned int hi = (c0 + 1 < CINC) ? lt[c0 + 1][px] : 0;
        pk[kk] = lo | (hi << 16);
    }
    unsigned short* dst = cT + (((size_t)(b*HH + y))*WW + x0 + px)*CPAD + cg*24;
    *(uint4*)(dst)      = make_uint4(pk[0], pk[1], pk[2], pk[3]);
    *(uint4*)(dst + 8)  = make_uint4(pk[4], pk[5], pk[6], pk[7]);
    *(uint4*)(dst + 16) = make_uint4(pk[8], pk[9], pk[10], pk[11]);
}

// ---------- fused layer: gate (dilated 3x3 + cond 1x1, tanh*sig) + res/skip 1x1 ----------
// block = 4 waves; tile 256(m, permuted) x 64(px). wave w owns m in [w*64, w*64+64).
__global__ __launch_bounds__(256, 4) void layer_fused(
        const unsigned short* __restrict__ hin, unsigned short* __restrict__ hout,
        const unsigned short* __restrict__ zrow, const unsigned short* __restrict__ cT,
        const unsigned short* __restrict__ gw, const float* __restrict__ gbias,
        const unsigned short* __restrict__ rw, const float* __restrict__ rbias,
        float* __restrict__ hf32, float* __restrict__ outskip,
        int layer, int dh, int dw) {
    __shared__ unsigned short sact[64 * CCH];   // 16 KB, XOR-swizzled [px][c]

    const int tid = threadIdx.x, lane = tid & 63, w = tid >> 6;
    const int lrow = lane & 15, lk = lane >> 4;
    const int x0 = blockIdx.x * 64, y = blockIdx.y, b = blockIdx.z;

    f32x4 acc[4][4];
#pragma unroll
    for (int mf = 0; mf < 4; ++mf)
#pragma unroll
        for (int nf = 0; nf < 4; ++nf) acc[mf][nf] = (f32x4){0.f, 0.f, 0.f, 0.f};

    const unsigned short* gwl = gw + (((size_t)layer*NQ*16) + w*4)*512 + lane*8;

    // precomputed tap base pointers (kh-row select to zero-row hoisted out)
    const unsigned short* tb[3][3];
    {
        const unsigned short* rowb[3];
#pragma unroll
        for (int kh = 0; kh < 3; ++kh) {
            int yin = y - (2 - kh)*dh;
            rowb[kh] = (yin >= 0) ? hin + ((size_t)(b*HH + yin))*WWP*CCH : zrow;
        }
#pragma unroll
        for (int kh = 0; kh < 3; ++kh)
#pragma unroll
            for (int kw = 0; kw < 3; ++kw)
                tb[kh][kw] = rowb[kh] + (size_t)(x0 + (kw - 1)*dw + PADW)*CCH + lk*8;
    }
    const unsigned short* cb = cT + (((size_t)(b*HH + y))*WW + x0)*CPAD + lk*8;

    auto loadf = [&](int tq, v8s (&av)[4], v8s (&bv)[4]) {
        const unsigned short* sp; int stq;
        if (tq < 36) {
            int tt = tq >> 2, q = tq & 3;
            int kh = tt / 3, kw = tt - kh*3;
            sp = tb[kh][kw] + q*32;
            stq = CCH;
        } else {
            sp = cb + (tq - 36)*32;
            stq = CPAD;
        }
        const unsigned short* gp = gwl + (size_t)tq*16*512;
#pragma unroll
        for (int mf = 0; mf < 4; ++mf) av[mf] = *(const v8s*)(gp + mf*512);
#pragma unroll
        for (int nf = 0; nf < 4; ++nf) bv[nf] = *(const v8s*)(sp + (size_t)(nf*16 + lrow)*stq);
    };
    auto mf16 = [&](v8s (&av)[4], v8s (&bv)[4]) {
#pragma unroll
        for (int mf = 0; mf < 4; ++mf)
#pragma unroll
            for (int nf = 0; nf < 4; ++nf)
                acc[mf][nf] = __builtin_amdgcn_mfma_f32_16x16x32_bf16(av[mf], bv[nf], acc[mf][nf], 0, 0, 0);
    };

    // 2-deep software pipeline over NQ=39 uniform k-steps, fully unrolled
    v8s avA[4], bvA[4], avB[4], bvB[4];
    loadf(0, avA, bvA);
#pragma unroll
    for (int t = 0; t < 37; t += 2) {
        loadf(t + 1, avB, bvB);
        mf16(avA, bvA);
        loadf(t + 2, avA, bvA);
        mf16(avB, bvB);
    }
    mf16(avA, bvA);   // tq = 38

    // ---- gated activation -> LDS (bf16, XOR-swizzled) ----
    const float* gb = gbias + layer*256;
#pragma unroll
    for (int mf = 0; mf < 4; ++mf) {
        int m0 = w*64 + mf*16 + lk*4;
        int c0 = m0 >> 1;                     // even
        float bF0 = gb[m0], bG0 = gb[m0+1], bF1 = gb[m0+2], bG1 = gb[m0+3];
#pragma unroll
        for (int nf = 0; nf < 4; ++nf) {
            int px = nf*16 + lrow;
            float o0 = tanhf(acc[mf][nf][0] + bF0) * sigm(acc[mf][nf][1] + bG0);
            float o1 = tanhf(acc[mf][nf][2] + bF1) * sigm(acc[mf][nf][3] + bG1);
            unsigned int pk = (unsigned int)f2bf(o0) | ((unsigned int)f2bf(o1) << 16);
            int byte = px*256 + c0*2;
            byte ^= (px & 7) << 4;
            *(unsigned int*)((char*)sact + byte) = pk;
        }
    }
    __syncthreads();

    // ---- res/skip 1x1 GEMM from LDS ----
    f32x4 racc[4][4];
#pragma unroll
    for (int mf = 0; mf < 4; ++mf)
#pragma unroll
        for (int nf = 0; nf < 4; ++nf) racc[mf][nf] = (f32x4){0.f, 0.f, 0.f, 0.f};

    const unsigned short* rwl = rw + (((size_t)layer*4*16) + w*4)*512 + lane*8;
#pragma unroll
    for (int q = 0; q < 4; ++q) {
        v8s av[4], bv[4];
#pragma unroll
        for (int mf = 0; mf < 4; ++mf) av[mf] = *(const v8s*)(rwl + (size_t)(q*16 + mf)*512);
#pragma unroll
        for (int nf = 0; nf < 4; ++nf) {
            int px = nf*16 + lrow;
            int byte = px*256 + q*64 + lk*16;
            byte ^= (px & 7) << 4;
            bv[nf] = *(const v8s*)((char*)sact + byte);
        }
#pragma unroll
        for (int mf = 0; mf < 4; ++mf)
#pragma unroll
            for (int nf = 0; nf < 4; ++nf)
                racc[mf][nf] = __builtin_amdgcn_mfma_f32_16x16x32_bf16(av[mf], bv[nf], racc[mf][nf], 0, 0, 0);
    }

    // ---- h += rs[:128] (fp32 plane-major + bf16 shadow); skip(d_out) += rs[128:] ----
    const float* rb = rbias + layer*256;
#pragma unroll
    for (int mf = 0; mf < 4; ++mf) {
        int m0 = w*64 + mf*16 + lk*4;
        int c0 = m0 >> 1;
        float bR0 = rb[m0], bS0 = rb[m0+1], bR1 = rb[m0+2], bS1 = rb[m0+3];
#pragma unroll
        for (int nf = 0; nf < 4; ++nf) {
            int px = x0 + nf*16 + lrow;
            size_t p0 = (((size_t)(b*CCH + c0))*HH + y)*WW + px;
            size_t p1 = p0 + (size_t)HW;
            float h0 = hf32[p0] + racc[mf][nf][0] + bR0;
            float h1 = hf32[p1] + racc[mf][nf][2] + bR1;
            hf32[p0] = h0;
            hf32[p1] = h1;
            unsigned int pk = (unsigned int)f2bf(h0) | ((unsigned int)f2bf(h1) << 16);
            *(unsigned int*)(hout + (((size_t)(b*HH + y))*WWP + px + PADW)*CCH + c0) = pk;
            outskip[p0] += racc[mf][nf][1] + bS0;
            outskip[p1] += racc[mf][nf][3] + bS1;
        }
    }
}

extern "C" void kernel_launch(void* const* d_in, const int* in_sizes, int n_in,
                              void* d_out, int out_size, void* d_ws, size_t ws_size,
                              hipStream_t stream) {
    const float* x       = (const float*)d_in[0];
    const float* c       = (const float*)d_in[1];
    const float* front_w = (const float*)d_in[2];
    const float* front_b = (const float*)d_in[3];
    const float* fg_w    = (const float*)d_in[4];
    const float* fg_b    = (const float*)d_in[5];
    const float* fgc_w   = (const float*)d_in[6];
    const float* fgc_b   = (const float*)d_in[7];
    const float* rs_w    = (const float*)d_in[8];
    const float* rs_b    = (const float*)d_in[9];

    char* ws = (char*)d_ws;
    float* hf32   = (float*)ws;                     ws += (size_t)HF32_N * 4;
    unsigned short* hbf0 = (unsigned short*)ws;     ws += (size_t)HBF_N * 2;
    unsigned short* hbf1 = (unsigned short*)ws;     ws += (size_t)HBF_N * 2;
    unsigned short* zrow = (unsigned short*)ws;     ws += (size_t)ZROW_N * 2;
    unsigned short* cT   = (unsigned short*)ws;     ws += (size_t)CT_N * 2;
    unsigned short* gw   = (unsigned short*)ws;     ws += (size_t)GW_N * 2;
    unsigned short* rwq  = (unsigned short*)ws;     ws += (size_t)RW_N * 2;
    float* gbias  = (float*)ws;                     ws += (size_t)NL * 256 * 4;
    float* rbias  = (float*)ws;

    float* outp = (float*)d_out;

    prep_weights<<<2048, 256, 0, stream>>>(fg_w, fgc_w, rs_w, fg_b, fgc_b, rs_b,
                                           gw, rwq, gbias, rbias);
    front_kernel<<<2048, 256, 0, stream>>>(x, front_w, front_b, hf32, hbf0, hbf1, zrow, outp);
    cond_transpose<<<dim3(64, 16, 2), 256, 0, stream>>>(c, cT);

    static const int DILH[NL] = {1, 2, 4, 8, 1, 2, 4, 8};
    static const int DILW[NL] = {1, 2, 4, 8, 16, 32, 64, 128};

    for (int i = 0; i < NL; ++i) {
        const unsigned short* hin = (i & 1) ? hbf1 : hbf0;
        unsigned short*       hout= (i & 1) ? hbf0 : hbf1;
        layer_fused<<<dim3(64, 16, 2), 256, 0, stream>>>(hin, hout, zrow, cT, gw, gbias,
                                                         rwq, rbias, hf32, outp,
                                                         i, DILH[i], DILW[i]);
    }
}

// Round 5
// 1474.755 us; speedup vs baseline: 4.6878x; 1.4476x over previous
//
#include <hip/hip_runtime.h>
#include <math.h>

#define NL    8
#define CCH   128
#define CINC  80
#define CPAD  128
#define HH    16
#define WW    4096
#define HW    (HH*WW)
#define PADW  128
#define WWP   (WW + 2*PADW)
#define NT    10            // 9 taps + 1 cond step (128ch each)

// workspace element counts
#define HF32_N  (2*HW*CCH)            // f32
#define HBF_N   (2*HH*WWP*CCH)        // u16 (per buffer)
#define ZROW_N  (WWP*CCH)             // u16
#define CT_N    (2*HW*CPAD)           // u16
#define GW_N    (NL*NT*4*16*64*8)     // u16
#define RW_N    (NL*4*16*64*8)        // u16

using v8s   = __attribute__((ext_vector_type(8))) short;
using f32x4 = __attribute__((ext_vector_type(4))) float;

__device__ __forceinline__ unsigned short f2bf(float f) {
    unsigned int u = __builtin_bit_cast(unsigned int, f);
    u += 0x7fffu + ((u >> 16) & 1u);
    return (unsigned short)(u >> 16);
}
__device__ __forceinline__ float sigm(float x) { return 1.0f / (1.0f + __expf(-x)); }

__device__ __forceinline__ void gl_lds16(const void* g, void* l) {
    __builtin_amdgcn_global_load_lds(
        (const __attribute__((address_space(1))) unsigned int*)g,
        (__attribute__((address_space(3))) unsigned int*)l, 16, 0, 0);
}

// ---------- one-time weight swizzle into MFMA A-fragment order ----------
// gw[i][t(10)][q(4)][mt(16)][lane(64)][j(8)]: A[m = mt*16 + (lane&15)][k = q*32 + 8*(lane>>4) + j]
// out-channel permutation: gemm row m -> original o = (m&1)*128 + (m>>1)
__global__ void prep_weights(const float* __restrict__ fg_w, const float* __restrict__ fgc_w,
                             const float* __restrict__ rs_w,
                             const float* __restrict__ fg_b, const float* __restrict__ fgc_b,
                             const float* __restrict__ rs_b,
                             unsigned short* __restrict__ gw, unsigned short* __restrict__ rw,
                             float* __restrict__ gbias, float* __restrict__ rbias) {
    const int total = GW_N + RW_N + 2 * NL * 256;
    const int stride = gridDim.x * blockDim.x;
    for (int idx = blockIdx.x * blockDim.x + threadIdx.x; idx < total; idx += stride) {
        if (idx < GW_N) {
            int t0 = idx;
            int j = t0 & 7;  t0 >>= 3;
            int l = t0 & 63; t0 >>= 6;
            int mt = t0 & 15; t0 >>= 4;
            int tq = t0 % (NT*4);
            int i  = t0 / (NT*4);
            int t  = tq >> 2, q = tq & 3;
            int m  = mt*16 + (l & 15);
            int oo = (m & 1)*128 + (m >> 1);
            int ci = q*32 + 8*(l >> 4) + j;
            float v;
            if (t < 9) {
                v = fg_w[(((size_t)i*256 + oo)*128 + ci)*9 + t];   // t == kh*3+kw
            } else {
                v = (ci < CINC) ? fgc_w[((size_t)i*256 + oo)*CINC + ci] : 0.0f;
            }
            gw[idx] = f2bf(v);
        } else if (idx < GW_N + RW_N) {
            int t0 = idx - GW_N;
            int j = t0 & 7;  t0 >>= 3;
            int l = t0 & 63; t0 >>= 6;
            int mt = t0 & 15; t0 >>= 4;
            int q = t0 & 3;
            int i = t0 >> 2;
            int m  = mt*16 + (l & 15);
            int oo = (m & 1)*128 + (m >> 1);
            int ci = q*32 + 8*(l >> 4) + j;
            rw[idx - GW_N] = f2bf(rs_w[((size_t)i*256 + oo)*128 + ci]);
        } else {
            int t0 = idx - GW_N - RW_N;
            if (t0 < NL*256) {
                int i = t0 >> 8, m = t0 & 255;
                int oo = (m & 1)*128 + (m >> 1);
                gbias[t0] = fg_b[i*256 + oo] + fgc_b[i*256 + oo];
            } else {
                t0 -= NL*256;
                int i = t0 >> 8, m = t0 & 255;
                int oo = (m & 1)*128 + (m >> 1);
                rbias[t0] = rs_b[i*256 + oo];
            }
        }
    }
}

// ---------- front 1x1 conv: hf32 (plane-major) + padded bf16 buf0; zero buf1/zrow/out ----------
__global__ void front_kernel(const float* __restrict__ xsrc,
                             const float* __restrict__ fw, const float* __restrict__ fb,
                             float* __restrict__ hf32, unsigned short* __restrict__ hbf0,
                             unsigned short* __restrict__ hbf1, unsigned short* __restrict__ zrow,
                             float* __restrict__ outskip) {
    const int stride = gridDim.x * blockDim.x;
    const int t0 = blockIdx.x * blockDim.x + threadIdx.x;
    for (int idx = t0; idx < HBF_N; idx += stride) {
        int c = idx & 127;
        int rest = idx >> 7;
        int xp = rest % WWP; rest /= WWP;
        int y = rest & 15;
        int b = rest >> 4;
        int x = xp - PADW;
        if (x >= 0 && x < WW) {
            float v = fw[c] * xsrc[((size_t)(b*HH + y))*WW + x] + fb[c];
            hbf0[idx] = f2bf(v);
            hf32[(((size_t)(b*CCH + c))*HH + y)*WW + x] = v;
        } else {
            hbf0[idx] = 0;
        }
    }
    for (int idx = t0; idx < HBF_N; idx += stride) hbf1[idx] = 0;
    for (int idx = t0; idx < ZROW_N; idx += stride) zrow[idx] = 0;
    for (int idx = t0; idx < HF32_N; idx += stride) outskip[idx] = 0.0f;
}

// ---------- conditioning transpose: c [b][80][y][x] f32 -> cT [b][y][x][128] bf16 (zero-padded) ----------
__global__ __launch_bounds__(256) void cond_transpose(const float* __restrict__ cin,
                                                      unsigned short* __restrict__ cT) {
    __shared__ unsigned short lt[CINC][72];
    const int tid = threadIdx.x, lane = tid & 63, w = tid >> 6;
    const int x0 = blockIdx.x * 64, y = blockIdx.y, b = blockIdx.z;
#pragma unroll
    for (int r = 0; r < 20; ++r) {
        int ci = w*20 + r;
        float v = cin[(((size_t)(b*CINC + ci))*HH + y)*WW + x0 + lane];
        lt[ci][lane] = f2bf(v);
    }
    __syncthreads();
    const int px = tid & 63, cg = tid >> 6;   // cg: 32 channels each
    unsigned int pk[16];
#pragma unroll
    for (int kk = 0; kk < 16; ++kk) {
        int c0 = cg*32 + kk*2;
        unsigned int lo = (c0     < CINC) ? lt[c0][px]     : 0;
        unsigned int hi = (c0 + 1 < CINC) ? lt[c0 + 1][px] : 0;
        pk[kk] = lo | (hi << 16);
    }
    unsigned short* dst = cT + (((size_t)(b*HH + y))*WW + x0 + px)*CPAD + cg*32;
#pragma unroll
    for (int u = 0; u < 4; ++u)
        *(uint4*)(dst + u*8) = make_uint4(pk[u*4], pk[u*4+1], pk[u*4+2], pk[u*4+3]);
}

// ---------- fused layer: gate (dilated 3x3 + cond 1x1, tanh*sig) + res/skip 1x1 ----------
// block = 4 waves; tile 256(m, permuted) x 64(px). wave w owns m in [w*64, w*64+64).
// B tiles staged to LDS (double-buffered, XOR-swizzled via pre-swizzled global src).
__global__ __launch_bounds__(256, 4) void layer_fused(
        const unsigned short* __restrict__ hin, unsigned short* __restrict__ hout,
        const unsigned short* __restrict__ zrow, const unsigned short* __restrict__ cT,
        const unsigned short* __restrict__ gw, const float* __restrict__ gbias,
        const unsigned short* __restrict__ rw, const float* __restrict__ rbias,
        float* __restrict__ hf32, float* __restrict__ outskip,
        int layer, int dh, int dw) {
    __shared__ char sbuf[2 * 16384];            // double-buffered B tile; buf0 reused as sact

    const int tid = threadIdx.x, lane = tid & 63, w = tid >> 6;
    const int lrow = lane & 15, lk = lane >> 4;
    const int x0 = blockIdx.x * 64, y = blockIdx.y, b = blockIdx.z;

    f32x4 acc[4][4];
#pragma unroll
    for (int mf = 0; mf < 4; ++mf)
#pragma unroll
        for (int nf = 0; nf < 4; ++nf) acc[mf][nf] = (f32x4){0.f, 0.f, 0.f, 0.f};

    // tap row bases (causal: yin<0 -> zero row)
    const unsigned short* rowb[3];
#pragma unroll
    for (int kh = 0; kh < 3; ++kh) {
        int yin = y - (2 - kh)*dh;
        rowb[kh] = (yin >= 0) ? hin + ((size_t)(b*HH + yin))*WWP*CCH : zrow;
    }
    const char* cb = (const char*)(cT + (((size_t)(b*HH + y))*WW + x0)*CPAD);

    // stage one 16KB tile (64px x 128ch bf16) with pre-swizzled source:
    // LDS[o] = tile[o ^ (((o>>8)&7)<<4)]  (involution; px = byte>>8)
    auto stage = [&](char* dst, const char* src) {
#pragma unroll
        for (int s = 0; s < 4; ++s) {
            unsigned o = (unsigned)(w*4 + s)*1024 + (unsigned)lane*16;
            unsigned g = o ^ (((o >> 8) & 7) << 4);
            gl_lds16(src + g, dst + (w*4 + s)*1024);
        }
    };
    auto dsread = [&](const char* bb, int q, v8s (&bv)[4]) {
#pragma unroll
        for (int nf = 0; nf < 4; ++nf) {
            int px = nf*16 + lrow;
            int o = px*256 + ((q*64 + lk*16) ^ ((lrow & 7) << 4));
            bv[nf] = *(const v8s*)(bb + o);
        }
    };
    auto loadAq = [&](const unsigned short* gq, int q, v8s (&av)[4]) {
#pragma unroll
        for (int mf = 0; mf < 4; ++mf)
            av[mf] = *(const v8s*)(gq + q*8192 + mf*512);
    };
    auto mf16 = [&](v8s (&av)[4], v8s (&bv)[4]) {
#pragma unroll
        for (int mf = 0; mf < 4; ++mf)
#pragma unroll
            for (int nf = 0; nf < 4; ++nf)
                acc[mf][nf] = __builtin_amdgcn_mfma_f32_16x16x32_bf16(av[mf], bv[nf], acc[mf][nf], 0, 0, 0);
    };

    // K-loop over 10 uniform 128-ch steps (9 taps + cond)
    {
        // prologue: stage step 0 (tap kh=0,kw=0)
        stage(sbuf, (const char*)(rowb[0] + (size_t)(x0 - dw + PADW)*CCH));
#pragma unroll
        for (int t = 0; t < NT; ++t) {
            __syncthreads();
            if (t < 9) {
                int tn = t + 1;
                const char* src;
                if (tn == 9) src = cb;
                else {
                    int kh = tn / 3, kw = tn - kh*3;
                    src = (const char*)(rowb[kh] + (size_t)(x0 + (kw - 1)*dw + PADW)*CCH);
                }
                stage(sbuf + ((t + 1) & 1)*16384, src);
            }
            const unsigned short* gq = gw + (((size_t)(layer*NT + t)*4*16) + w*4)*512 + lane*8;
            char* bb = sbuf + (t & 1)*16384;
            v8s aA[4], aB[4], bv[4];
            loadAq(gq, 0, aA); loadAq(gq, 1, aB);
            dsread(bb, 0, bv); mf16(aA, bv);
            loadAq(gq, 2, aA);
            dsread(bb, 1, bv); mf16(aB, bv);
            loadAq(gq, 3, aB);
            dsread(bb, 2, bv); mf16(aA, bv);
            dsread(bb, 3, bv); mf16(aB, bv);
        }
    }

    // ---- gated activation -> LDS (bf16, XOR-swizzled), reusing buf0 ----
    char* sact = sbuf;
    const float* gb = gbias + layer*256;
#pragma unroll
    for (int mf = 0; mf < 4; ++mf) {
        int m0 = w*64 + mf*16 + lk*4;
        int c0 = m0 >> 1;                     // even
        float bF0 = gb[m0], bG0 = gb[m0+1], bF1 = gb[m0+2], bG1 = gb[m0+3];
#pragma unroll
        for (int nf = 0; nf < 4; ++nf) {
            int px = nf*16 + lrow;
            float o0 = tanhf(acc[mf][nf][0] + bF0) * sigm(acc[mf][nf][1] + bG0);
            float o1 = tanhf(acc[mf][nf][2] + bF1) * sigm(acc[mf][nf][3] + bG1);
            unsigned int pk = (unsigned int)f2bf(o0) | ((unsigned int)f2bf(o1) << 16);
            int byte = px*256 + c0*2;
            byte ^= (px & 7) << 4;
            *(unsigned int*)(sact + byte) = pk;
        }
    }
    __syncthreads();

    // ---- res/skip 1x1 GEMM from LDS ----
    f32x4 racc[4][4];
#pragma unroll
    for (int mf = 0; mf < 4; ++mf)
#pragma unroll
        for (int nf = 0; nf < 4; ++nf) racc[mf][nf] = (f32x4){0.f, 0.f, 0.f, 0.f};

    const unsigned short* rwl = rw + (((size_t)layer*4*16) + w*4)*512 + lane*8;
#pragma unroll
    for (int q = 0; q < 4; ++q) {
        v8s av[4], bv[4];
#pragma unroll
        for (int mf = 0; mf < 4; ++mf) av[mf] = *(const v8s*)(rwl + (size_t)(q*16 + mf)*512);
#pragma unroll
        for (int nf = 0; nf < 4; ++nf) {
            int px = nf*16 + lrow;
            int byte = px*256 + q*64 + lk*16;
            byte ^= (px & 7) << 4;
            bv[nf] = *(const v8s*)(sact + byte);
        }
#pragma unroll
        for (int mf = 0; mf < 4; ++mf)
#pragma unroll
            for (int nf = 0; nf < 4; ++nf)
                racc[mf][nf] = __builtin_amdgcn_mfma_f32_16x16x32_bf16(av[mf], bv[nf], racc[mf][nf], 0, 0, 0);
    }

    // ---- h += rs[:128] (fp32 plane-major + bf16 shadow); skip(d_out) += rs[128:] ----
    const float* rb = rbias + layer*256;
#pragma unroll
    for (int mf = 0; mf < 4; ++mf) {
        int m0 = w*64 + mf*16 + lk*4;
        int c0 = m0 >> 1;
        float bR0 = rb[m0], bS0 = rb[m0+1], bR1 = rb[m0+2], bS1 = rb[m0+3];
#pragma unroll
        for (int nf = 0; nf < 4; ++nf) {
            int px = x0 + nf*16 + lrow;
            size_t p0 = (((size_t)(b*CCH + c0))*HH + y)*WW + px;
            size_t p1 = p0 + (size_t)HW;
            float h0 = hf32[p0] + racc[mf][nf][0] + bR0;
            float h1 = hf32[p1] + racc[mf][nf][2] + bR1;
            hf32[p0] = h0;
            hf32[p1] = h1;
            unsigned int pk = (unsigned int)f2bf(h0) | ((unsigned int)f2bf(h1) << 16);
            *(unsigned int*)(hout + (((size_t)(b*HH + y))*WWP + px + PADW)*CCH + c0) = pk;
            outskip[p0] += racc[mf][nf][1] + bS0;
            outskip[p1] += racc[mf][nf][3] + bS1;
        }
    }
}

extern "C" void kernel_launch(void* const* d_in, const int* in_sizes, int n_in,
                              void* d_out, int out_size, void* d_ws, size_t ws_size,
                              hipStream_t stream) {
    const float* x       = (const float*)d_in[0];
    const float* c       = (const float*)d_in[1];
    const float* front_w = (const float*)d_in[2];
    const float* front_b = (const float*)d_in[3];
    const float* fg_w    = (const float*)d_in[4];
    const float* fg_b    = (const float*)d_in[5];
    const float* fgc_w   = (const float*)d_in[6];
    const float* fgc_b   = (const float*)d_in[7];
    const float* rs_w    = (const float*)d_in[8];
    const float* rs_b    = (const float*)d_in[9];

    char* ws = (char*)d_ws;
    float* hf32   = (float*)ws;                     ws += (size_t)HF32_N * 4;
    unsigned short* hbf0 = (unsigned short*)ws;     ws += (size_t)HBF_N * 2;
    unsigned short* hbf1 = (unsigned short*)ws;     ws += (size_t)HBF_N * 2;
    unsigned short* zrow = (unsigned short*)ws;     ws += (size_t)ZROW_N * 2;
    unsigned short* cT   = (unsigned short*)ws;     ws += (size_t)CT_N * 2;
    unsigned short* gw   = (unsigned short*)ws;     ws += (size_t)GW_N * 2;
    unsigned short* rwq  = (unsigned short*)ws;     ws += (size_t)RW_N * 2;
    float* gbias  = (float*)ws;                     ws += (size_t)NL * 256 * 4;
    float* rbias  = (float*)ws;

    float* outp = (float*)d_out;

    prep_weights<<<2048, 256, 0, stream>>>(fg_w, fgc_w, rs_w, fg_b, fgc_b, rs_b,
                                           gw, rwq, gbias, rbias);
    front_kernel<<<2048, 256, 0, stream>>>(x, front_w, front_b, hf32, hbf0, hbf1, zrow, outp);
    cond_transpose<<<dim3(64, 16, 2), 256, 0, stream>>>(c, cT);

    static const int DILH[NL] = {1, 2, 4, 8, 1, 2, 4, 8};
    static const int DILW[NL] = {1, 2, 4, 8, 16, 32, 64, 128};

    for (int i = 0; i < NL; ++i) {
        const unsigned short* hin = (i & 1) ? hbf1 : hbf0;
        unsigned short*       hout= (i & 1) ? hbf0 : hbf1;
        layer_fused<<<dim3(64, 16, 2), 256, 0, stream>>>(hin, hout, zrow, cT, gw, gbias,
                                                         rwq, rbias, hf32, outp,
                                                         i, DILH[i], DILW[i]);
    }
}

// Round 6
// 1193.237 us; speedup vs baseline: 5.7938x; 1.2359x over previous
//
#include <hip/hip_runtime.h>
#include <math.h>

#define NL    8
#define CCH   128
#define CINC  80
#define CPAD  128
#define HH    16
#define WW    4096
#define HW    (HH*WW)
#define PADW  128
#define WWP   (WW + 2*PADW)
#define NT    10            // 9 taps + 1 cond step (128ch each)

// workspace element counts
#define HF32_N  (2*HW*CCH)            // f32
#define HBF_N   (2*HH*WWP*CCH)        // u16 (per buffer)
#define ZROW_N  (WWP*CCH)             // u16
#define CT_N    (2*HW*CPAD)           // u16
#define GW_N    (NL*NT*4*16*64*8)     // u16
#define RW_N    (NL*4*16*64*8)        // u16

using v8s   = __attribute__((ext_vector_type(8))) short;
using f32x4 = __attribute__((ext_vector_type(4))) float;

__device__ __forceinline__ unsigned short f2bf(float f) {
    unsigned int u = __builtin_bit_cast(unsigned int, f);
    u += 0x7fffu + ((u >> 16) & 1u);
    return (unsigned short)(u >> 16);
}
__device__ __forceinline__ float sigm(float x) { return 1.0f / (1.0f + __expf(-x)); }

__device__ __forceinline__ void gl_lds16(const void* g, void* l) {
    __builtin_amdgcn_global_load_lds(
        (const __attribute__((address_space(1))) unsigned int*)g,
        (__attribute__((address_space(3))) unsigned int*)l, 16, 0, 0);
}

// ---------- one-time weight swizzle into MFMA A-fragment order ----------
// gw[i][t(10)][q(4)][mt(16)][lane(64)][j(8)]: A[m = mt*16 + (lane&15)][k = q*32 + 8*(lane>>4) + j]
// out-channel permutation: gemm row m -> original o = (m&1)*128 + (m>>1)
__global__ void prep_weights(const float* __restrict__ fg_w, const float* __restrict__ fgc_w,
                             const float* __restrict__ rs_w,
                             const float* __restrict__ fg_b, const float* __restrict__ fgc_b,
                             const float* __restrict__ rs_b,
                             unsigned short* __restrict__ gw, unsigned short* __restrict__ rw,
                             float* __restrict__ gbias, float* __restrict__ rbias) {
    const int total = GW_N + RW_N + 2 * NL * 256;
    const int stride = gridDim.x * blockDim.x;
    for (int idx = blockIdx.x * blockDim.x + threadIdx.x; idx < total; idx += stride) {
        if (idx < GW_N) {
            int t0 = idx;
            int j = t0 & 7;  t0 >>= 3;
            int l = t0 & 63; t0 >>= 6;
            int mt = t0 & 15; t0 >>= 4;
            int tq = t0 % (NT*4);
            int i  = t0 / (NT*4);
            int t  = tq >> 2, q = tq & 3;
            int m  = mt*16 + (l & 15);
            int oo = (m & 1)*128 + (m >> 1);
            int ci = q*32 + 8*(l >> 4) + j;
            float v;
            if (t < 9) {
                v = fg_w[(((size_t)i*256 + oo)*128 + ci)*9 + t];   // t == kh*3+kw
            } else {
                v = (ci < CINC) ? fgc_w[((size_t)i*256 + oo)*CINC + ci] : 0.0f;
            }
            gw[idx] = f2bf(v);
        } else if (idx < GW_N + RW_N) {
            int t0 = idx - GW_N;
            int j = t0 & 7;  t0 >>= 3;
            int l = t0 & 63; t0 >>= 6;
            int mt = t0 & 15; t0 >>= 4;
            int q = t0 & 3;
            int i = t0 >> 2;
            int m  = mt*16 + (l & 15);
            int oo = (m & 1)*128 + (m >> 1);
            int ci = q*32 + 8*(l >> 4) + j;
            rw[idx - GW_N] = f2bf(rs_w[((size_t)i*256 + oo)*128 + ci]);
        } else {
            int t0 = idx - GW_N - RW_N;
            if (t0 < NL*256) {
                int i = t0 >> 8, m = t0 & 255;
                int oo = (m & 1)*128 + (m >> 1);
                gbias[t0] = fg_b[i*256 + oo] + fgc_b[i*256 + oo];
            } else {
                t0 -= NL*256;
                int i = t0 >> 8, m = t0 & 255;
                int oo = (m & 1)*128 + (m >> 1);
                rbias[t0] = rs_b[i*256 + oo];
            }
        }
    }
}

// ---------- front 1x1 conv: hf32 (plane-major, coalesced) + padded bf16 buf0; zero buf1 pads/zrow ----------
__global__ void front_kernel(const float* __restrict__ xsrc,
                             const float* __restrict__ fw, const float* __restrict__ fb,
                             float* __restrict__ hf32, unsigned short* __restrict__ hbf0,
                             unsigned short* __restrict__ hbf1, unsigned short* __restrict__ zrow) {
    const int stride = gridDim.x * blockDim.x;
    const int t0 = blockIdx.x * blockDim.x + threadIdx.x;
    // hf32 plane-major [b][c][y][x], x innermost -> coalesced writes & reads
    for (int idx = t0; idx < HF32_N; idx += stride) {
        int x = idx & (WW - 1);
        int y = (idx >> 12) & 15;
        int c = (idx >> 16) & 127;
        int b = idx >> 23;
        hf32[idx] = fw[c] * xsrc[((size_t)(b*HH + y))*WW + x] + fb[c];
    }
    // hbf0 padded [b][y][xp][c], c innermost -> coalesced writes
    for (int idx = t0; idx < HBF_N; idx += stride) {
        int c = idx & 127;
        int rest = idx >> 7;
        int xp = rest % WWP; rest /= WWP;
        int y = rest & 15;
        int b = rest >> 4;
        int x = xp - PADW;
        if (x >= 0 && x < WW) {
            hbf0[idx] = f2bf(fw[c] * xsrc[((size_t)(b*HH + y))*WW + x] + fb[c]);
        } else {
            hbf0[idx] = 0;
        }
    }
    // hbf1: zero ONLY the pad columns (interior is fully overwritten by layer 0)
    const int PADN = 2*HH*2*PADW*CCH;
    for (int idx = t0; idx < PADN; idx += stride) {
        int c = idx & 127;
        int r = idx >> 7;
        int xo = r % (2*PADW); r /= (2*PADW);
        int y = r & 15;
        int b = r >> 4;
        int xp = (xo < PADW) ? xo : xo + WW;   // left pad or right pad
        hbf1[(((size_t)(b*HH + y))*WWP + xp)*CCH + c] = 0;
    }
    for (int idx = t0; idx < ZROW_N; idx += stride) zrow[idx] = 0;
}

// ---------- conditioning transpose: c [b][80][y][x] f32 -> cT [b][y][x][128] bf16 (zero-padded) ----------
__global__ __launch_bounds__(256) void cond_transpose(const float* __restrict__ cin,
                                                      unsigned short* __restrict__ cT) {
    __shared__ unsigned short lt[CINC][72];
    const int tid = threadIdx.x, lane = tid & 63, w = tid >> 6;
    const int x0 = blockIdx.x * 64, y = blockIdx.y, b = blockIdx.z;
#pragma unroll
    for (int r = 0; r < 20; ++r) {
        int ci = w*20 + r;
        float v = cin[(((size_t)(b*CINC + ci))*HH + y)*WW + x0 + lane];
        lt[ci][lane] = f2bf(v);
    }
    __syncthreads();
    const int px = tid & 63, cg = tid >> 6;   // cg: 32 channels each
    unsigned int pk[16];
#pragma unroll
    for (int kk = 0; kk < 16; ++kk) {
        int c0 = cg*32 + kk*2;
        unsigned int lo = (c0     < CINC) ? lt[c0][px]     : 0;
        unsigned int hi = (c0 + 1 < CINC) ? lt[c0 + 1][px] : 0;
        pk[kk] = lo | (hi << 16);
    }
    unsigned short* dst = cT + (((size_t)(b*HH + y))*WW + x0 + px)*CPAD + cg*32;
#pragma unroll
    for (int u = 0; u < 4; ++u)
        *(uint4*)(dst + u*8) = make_uint4(pk[u*4], pk[u*4+1], pk[u*4+2], pk[u*4+3]);
}

// ---------- fused layer: gate (dilated 3x3 + cond 1x1, tanh*sig) + res/skip 1x1 ----------
// block = 4 waves; tile 256(m, permuted) x 64(px). wave w owns m in [w*64, w*64+64).
// B tiles staged to LDS: 3-buffer circular, counted vmcnt (T3/T4-lite), XOR-swizzled.
__global__ __launch_bounds__(256) void layer_fused(
        const unsigned short* __restrict__ hin, unsigned short* __restrict__ hout,
        const unsigned short* __restrict__ zrow, const unsigned short* __restrict__ cT,
        const unsigned short* __restrict__ gw, const float* __restrict__ gbias,
        const unsigned short* __restrict__ rw, const float* __restrict__ rbias,
        float* __restrict__ hf32, float* __restrict__ outskip,
        int layer, int dh, int dw, int first) {
    __shared__ char sbuf[3 * 16384];            // 3-buffer circular staging; buf2 reused as sact

    const int tid = threadIdx.x, lane = tid & 63, w = tid >> 6;
    const int lrow = lane & 15, lk = lane >> 4;
    const int x0 = blockIdx.x * 64, y = blockIdx.y, b = blockIdx.z;

    f32x4 acc[4][4];
#pragma unroll
    for (int mf = 0; mf < 4; ++mf)
#pragma unroll
        for (int nf = 0; nf < 4; ++nf) acc[mf][nf] = (f32x4){0.f, 0.f, 0.f, 0.f};

    // tap row bases (causal: yin<0 -> zero row)
    const unsigned short* rowb[3];
#pragma unroll
    for (int kh = 0; kh < 3; ++kh) {
        int yin = y - (2 - kh)*dh;
        rowb[kh] = (yin >= 0) ? hin + ((size_t)(b*HH + yin))*WWP*CCH : zrow;
    }
    const char* cb = (const char*)(cT + (((size_t)(b*HH + y))*WW + x0)*CPAD);

    // stage one 16KB tile (64px x 128ch bf16) with pre-swizzled source:
    // LDS[o] = tile[o ^ (((o>>8)&7)<<4)]  (involution; px = byte>>8)
    auto stage = [&](char* dst, const char* src) {
#pragma unroll
        for (int s = 0; s < 4; ++s) {
            unsigned o = (unsigned)(w*4 + s)*1024 + (unsigned)lane*16;
            unsigned g = o ^ (((o >> 8) & 7) << 4);
            gl_lds16(src + g, dst + (w*4 + s)*1024);
        }
    };
    auto stage_t = [&](int t) {
        const char* src;
        if (t == 9) src = cb;
        else {
            int kh = t / 3, kw = t - kh*3;
            src = (const char*)(rowb[kh] + (size_t)(x0 + (kw - 1)*dw + PADW)*CCH);
        }
        stage(sbuf + (t % 3)*16384, src);
    };
    auto dsread = [&](const char* bb, int q, v8s (&bv)[4]) {
#pragma unroll
        for (int nf = 0; nf < 4; ++nf) {
            int px = nf*16 + lrow;
            int o = px*256 + ((q*64 + lk*16) ^ ((lrow & 7) << 4));
            bv[nf] = *(const v8s*)(bb + o);
        }
    };
    auto mf16 = [&](v8s (&av)[4], v8s (&bv)[4]) {
#pragma unroll
        for (int mf = 0; mf < 4; ++mf)
#pragma unroll
            for (int nf = 0; nf < 4; ++nf)
                acc[mf][nf] = __builtin_amdgcn_mfma_f32_16x16x32_bf16(av[mf], bv[nf], acc[mf][nf], 0, 0, 0);
    };

    // ---- K-loop: 10 uniform 128-ch steps (9 taps + cond), counted-vmcnt pipeline ----
    stage_t(0);
    stage_t(1);
#pragma unroll
    for (int t = 0; t < NT; ++t) {
        const unsigned short* gq = gw + (((size_t)(layer*NT + t)*4*16) + w*4)*512 + lane*8;
        // all 16 A-fragments for this step (L2-resident weights)
        v8s av[4][4];
#pragma unroll
        for (int q = 0; q < 4; ++q)
#pragma unroll
            for (int mf = 0; mf < 4; ++mf)
                av[q][mf] = *(const v8s*)(gq + q*8192 + mf*512);
        // wait for stage(t) to land (counted: newer = A_t(16) + stage(t+1)(4) [+ A_{t-1}(16)])
        if (t == 0) asm volatile("s_waitcnt vmcnt(20)" ::: "memory");
        else        asm volatile("s_waitcnt vmcnt(32)" ::: "memory");
        __builtin_amdgcn_sched_barrier(0);
        __builtin_amdgcn_s_barrier();
        __builtin_amdgcn_sched_barrier(0);
        if (t + 2 < NT) stage_t(t + 2);     // prefetch 2 ahead (buffer read at t-1, all done)
        const char* bb = sbuf + (t % 3)*16384;
        v8s bv[4];
#pragma unroll
        for (int q = 0; q < 4; ++q) {
            dsread(bb, q, bv);
            mf16(av[q], bv);
        }
    }

    // ---- gated activation -> LDS (bf16, XOR-swizzled), in buf2 (last read at t=8, barrier-safe) ----
    char* sact = sbuf + 2*16384;
    const float* gb = gbias + layer*256;
#pragma unroll
    for (int mf = 0; mf < 4; ++mf) {
        int m0 = w*64 + mf*16 + lk*4;
        int c0 = m0 >> 1;                     // even
        float bF0 = gb[m0], bG0 = gb[m0+1], bF1 = gb[m0+2], bG1 = gb[m0+3];
#pragma unroll
        for (int nf = 0; nf < 4; ++nf) {
            int px = nf*16 + lrow;
            float o0 = tanhf(acc[mf][nf][0] + bF0) * sigm(acc[mf][nf][1] + bG0);
            float o1 = tanhf(acc[mf][nf][2] + bF1) * sigm(acc[mf][nf][3] + bG1);
            unsigned int pk = (unsigned int)f2bf(o0) | ((unsigned int)f2bf(o1) << 16);
            int byte = px*256 + c0*2;
            byte ^= (px & 7) << 4;
            *(unsigned int*)(sact + byte) = pk;
        }
    }
    __syncthreads();

    // ---- res/skip 1x1 GEMM from LDS ----
    f32x4 racc[4][4];
#pragma unroll
    for (int mf = 0; mf < 4; ++mf)
#pragma unroll
        for (int nf = 0; nf < 4; ++nf) racc[mf][nf] = (f32x4){0.f, 0.f, 0.f, 0.f};

    const unsigned short* rwl = rw + (((size_t)layer*4*16) + w*4)*512 + lane*8;
#pragma unroll
    for (int q = 0; q < 4; ++q) {
        v8s av[4], bv[4];
#pragma unroll
        for (int mf = 0; mf < 4; ++mf) av[mf] = *(const v8s*)(rwl + (size_t)(q*16 + mf)*512);
#pragma unroll
        for (int nf = 0; nf < 4; ++nf) {
            int px = nf*16 + lrow;
            int byte = px*256 + q*64 + lk*16;
            byte ^= (px & 7) << 4;
            bv[nf] = *(const v8s*)(sact + byte);
        }
#pragma unroll
        for (int mf = 0; mf < 4; ++mf)
#pragma unroll
            for (int nf = 0; nf < 4; ++nf)
                racc[mf][nf] = __builtin_amdgcn_mfma_f32_16x16x32_bf16(av[mf], bv[nf], racc[mf][nf], 0, 0, 0);
    }

    // ---- h += rs[:128] (fp32 plane-major + bf16 shadow); skip(d_out) =/+= rs[128:] ----
    const float* rb = rbias + layer*256;
#pragma unroll
    for (int mf = 0; mf < 4; ++mf) {
        int m0 = w*64 + mf*16 + lk*4;
        int c0 = m0 >> 1;
        float bR0 = rb[m0], bS0 = rb[m0+1], bR1 = rb[m0+2], bS1 = rb[m0+3];
#pragma unroll
        for (int nf = 0; nf < 4; ++nf) {
            int px = x0 + nf*16 + lrow;
            size_t p0 = (((size_t)(b*CCH + c0))*HH + y)*WW + px;
            size_t p1 = p0 + (size_t)HW;
            float h0 = hf32[p0] + racc[mf][nf][0] + bR0;
            float h1 = hf32[p1] + racc[mf][nf][2] + bR1;
            hf32[p0] = h0;
            hf32[p1] = h1;
            unsigned int pk = (unsigned int)f2bf(h0) | ((unsigned int)f2bf(h1) << 16);
            *(unsigned int*)(hout + (((size_t)(b*HH + y))*WWP + px + PADW)*CCH + c0) = pk;
            float s0 = racc[mf][nf][1] + bS0;
            float s1 = racc[mf][nf][3] + bS1;
            if (first) {
                outskip[p0] = s0;
                outskip[p1] = s1;
            } else {
                outskip[p0] += s0;
                outskip[p1] += s1;
            }
        }
    }
}

extern "C" void kernel_launch(void* const* d_in, const int* in_sizes, int n_in,
                              void* d_out, int out_size, void* d_ws, size_t ws_size,
                              hipStream_t stream) {
    const float* x       = (const float*)d_in[0];
    const float* c       = (const float*)d_in[1];
    const float* front_w = (const float*)d_in[2];
    const float* front_b = (const float*)d_in[3];
    const float* fg_w    = (const float*)d_in[4];
    const float* fg_b    = (const float*)d_in[5];
    const float* fgc_w   = (const float*)d_in[6];
    const float* fgc_b   = (const float*)d_in[7];
    const float* rs_w    = (const float*)d_in[8];
    const float* rs_b    = (const float*)d_in[9];

    char* ws = (char*)d_ws;
    float* hf32   = (float*)ws;                     ws += (size_t)HF32_N * 4;
    unsigned short* hbf0 = (unsigned short*)ws;     ws += (size_t)HBF_N * 2;
    unsigned short* hbf1 = (unsigned short*)ws;     ws += (size_t)HBF_N * 2;
    unsigned short* zrow = (unsigned short*)ws;     ws += (size_t)ZROW_N * 2;
    unsigned short* cT   = (unsigned short*)ws;     ws += (size_t)CT_N * 2;
    unsigned short* gw   = (unsigned short*)ws;     ws += (size_t)GW_N * 2;
    unsigned short* rwq  = (unsigned short*)ws;     ws += (size_t)RW_N * 2;
    float* gbias  = (float*)ws;                     ws += (size_t)NL * 256 * 4;
    float* rbias  = (float*)ws;

    float* outp = (float*)d_out;

    prep_weights<<<2048, 256, 0, stream>>>(fg_w, fgc_w, rs_w, fg_b, fgc_b, rs_b,
                                           gw, rwq, gbias, rbias);
    front_kernel<<<2048, 256, 0, stream>>>(x, front_w, front_b, hf32, hbf0, hbf1, zrow);
    cond_transpose<<<dim3(64, 16, 2), 256, 0, stream>>>(c, cT);

    static const int DILH[NL] = {1, 2, 4, 8, 1, 2, 4, 8};
    static const int DILW[NL] = {1, 2, 4, 8, 16, 32, 64, 128};

    for (int i = 0; i < NL; ++i) {
        const unsigned short* hin = (i & 1) ? hbf1 : hbf0;
        unsigned short*       hout= (i & 1) ? hbf0 : hbf1;
        layer_fused<<<dim3(64, 16, 2), 256, 0, stream>>>(hin, hout, zrow, cT, gw, gbias,
                                                         rwq, rbias, hf32, outp,
                                                         i, DILH[i], DILW[i], i == 0 ? 1 : 0);
    }
}

// Round 8
// 1138.413 us; speedup vs baseline: 6.0729x; 1.0482x over previous
//
#include <hip/hip_runtime.h>
#include <math.h>

#define NL    8
#define CCH   128
#define CINC  80
#define CPAD  128
#define HH    16
#define WW    4096
#define HW    (HH*WW)
#define PADW  128
#define WWP   (WW + 2*PADW)
#define NT    10            // 9 taps + 1 cond step (128ch each)
#define PADF  68            // f32 row stride for sres transpose (17*4, odd multiple of 4)

// workspace element counts  (total ~171 MB, proven in R6)
#define HF32_N  (2*HW*CCH)            // f32
#define HBF_N   (2*HH*WWP*CCH)        // u16 (per buffer)
#define ZROW_N  (WWP*CCH)             // u16
#define CT_N    (2*HW*CPAD)           // u16
#define GW_N    (NL*NT*4*16*64*8)     // u16
#define RW_N    (NL*4*16*64*8)        // u16

using v8s   = __attribute__((ext_vector_type(8))) short;
using f32x4 = __attribute__((ext_vector_type(4))) float;

__device__ __forceinline__ unsigned short f2bf(float f) {
    unsigned int u = __builtin_bit_cast(unsigned int, f);
    u += 0x7fffu + ((u >> 16) & 1u);
    return (unsigned short)(u >> 16);
}
__device__ __forceinline__ float sigm(float x) { return 1.0f / (1.0f + __expf(-x)); }

__device__ __forceinline__ void gl_lds16(const void* g, void* l) {
    __builtin_amdgcn_global_load_lds(
        (const __attribute__((address_space(1))) unsigned int*)g,
        (__attribute__((address_space(3))) unsigned int*)l, 16, 0, 0);
}

// ---------- one-time weight swizzle into MFMA A-fragment order ----------
// gw[i][t(10)][q(4)][mt(16)][lane(64)][j(8)]: A[m = mt*16 + (lane&15)][k = q*32 + 8*(lane>>4) + j]
// out-channel permutation: gemm row m -> original o = (m&1)*128 + (m>>1)
__global__ void prep_weights(const float* __restrict__ fg_w, const float* __restrict__ fgc_w,
                             const float* __restrict__ rs_w,
                             const float* __restrict__ fg_b, const float* __restrict__ fgc_b,
                             const float* __restrict__ rs_b,
                             unsigned short* __restrict__ gw, unsigned short* __restrict__ rw,
                             float* __restrict__ gbias, float* __restrict__ rbias) {
    const int total = GW_N + RW_N + 2 * NL * 256;
    const int stride = gridDim.x * blockDim.x;
    for (int idx = blockIdx.x * blockDim.x + threadIdx.x; idx < total; idx += stride) {
        if (idx < GW_N) {
            int t0 = idx;
            int j = t0 & 7;  t0 >>= 3;
            int l = t0 & 63; t0 >>= 6;
            int mt = t0 & 15; t0 >>= 4;
            int tq = t0 % (NT*4);
            int i  = t0 / (NT*4);
            int t  = tq >> 2, q = tq & 3;
            int m  = mt*16 + (l & 15);
            int oo = (m & 1)*128 + (m >> 1);
            int ci = q*32 + 8*(l >> 4) + j;
            float v;
            if (t < 9) {
                v = fg_w[(((size_t)i*256 + oo)*128 + ci)*9 + t];   // t == kh*3+kw
            } else {
                v = (ci < CINC) ? fgc_w[((size_t)i*256 + oo)*CINC + ci] : 0.0f;
            }
            gw[idx] = f2bf(v);
        } else if (idx < GW_N + RW_N) {
            int t0 = idx - GW_N;
            int j = t0 & 7;  t0 >>= 3;
            int l = t0 & 63; t0 >>= 6;
            int mt = t0 & 15; t0 >>= 4;
            int q = t0 & 3;
            int i = t0 >> 2;
            int m  = mt*16 + (l & 15);
            int oo = (m & 1)*128 + (m >> 1);
            int ci = q*32 + 8*(l >> 4) + j;
            rw[idx - GW_N] = f2bf(rs_w[((size_t)i*256 + oo)*128 + ci]);
        } else {
            int t0 = idx - GW_N - RW_N;
            if (t0 < NL*256) {
                int i = t0 >> 8, m = t0 & 255;
                int oo = (m & 1)*128 + (m >> 1);
                gbias[t0] = fg_b[i*256 + oo] + fgc_b[i*256 + oo];
            } else {
                t0 -= NL*256;
                int i = t0 >> 8, m = t0 & 255;
                int oo = (m & 1)*128 + (m >> 1);
                rbias[t0] = rs_b[i*256 + oo];
            }
        }
    }
}

// ---------- front 1x1 conv: hf32 (plane-major, coalesced) + padded bf16 buf0; zero buf1 pads/zrow ----------
__global__ void front_kernel(const float* __restrict__ xsrc,
                             const float* __restrict__ fw, const float* __restrict__ fb,
                             float* __restrict__ hf32, unsigned short* __restrict__ hbf0,
                             unsigned short* __restrict__ hbf1, unsigned short* __restrict__ zrow) {
    const int stride = gridDim.x * blockDim.x;
    const int t0 = blockIdx.x * blockDim.x + threadIdx.x;
    for (int idx = t0; idx < HF32_N; idx += stride) {
        int x = idx & (WW - 1);
        int y = (idx >> 12) & 15;
        int c = (idx >> 16) & 127;
        int b = idx >> 23;
        hf32[idx] = fw[c] * xsrc[((size_t)(b*HH + y))*WW + x] + fb[c];
    }
    for (int idx = t0; idx < HBF_N; idx += stride) {
        int c = idx & 127;
        int rest = idx >> 7;
        int xp = rest % WWP; rest /= WWP;
        int y = rest & 15;
        int b = rest >> 4;
        int x = xp - PADW;
        if (x >= 0 && x < WW)
            hbf0[idx] = f2bf(fw[c] * xsrc[((size_t)(b*HH + y))*WW + x] + fb[c]);
        else
            hbf0[idx] = 0;
    }
    const int PADN = 2*HH*2*PADW*CCH;
    for (int idx = t0; idx < PADN; idx += stride) {
        int c = idx & 127;
        int r = idx >> 7;
        int xo = r % (2*PADW); r /= (2*PADW);
        int y = r & 15;
        int b = r >> 4;
        int xp = (xo < PADW) ? xo : xo + WW;
        hbf1[(((size_t)(b*HH + y))*WWP + xp)*CCH + c] = 0;
    }
    for (int idx = t0; idx < ZROW_N; idx += stride) zrow[idx] = 0;
}

// ---------- conditioning transpose: c [b][80][y][x] f32 -> cT [b][y][x][128] bf16 (zero-padded) ----------
__global__ __launch_bounds__(256) void cond_transpose(const float* __restrict__ cin,
                                                      unsigned short* __restrict__ cT) {
    __shared__ unsigned short lt[CINC][72];
    const int tid = threadIdx.x, lane = tid & 63, w = tid >> 6;
    const int x0 = blockIdx.x * 64, y = blockIdx.y, b = blockIdx.z;
#pragma unroll
    for (int r = 0; r < 20; ++r) {
        int ci = w*20 + r;
        float v = cin[(((size_t)(b*CINC + ci))*HH + y)*WW + x0 + lane];
        lt[ci][lane] = f2bf(v);
    }
    __syncthreads();
    const int px = tid & 63, cg = tid >> 6;
    unsigned int pk[16];
#pragma unroll
    for (int kk = 0; kk < 16; ++kk) {
        int c0 = cg*32 + kk*2;
        unsigned int lo = (c0     < CINC) ? lt[c0][px]     : 0;
        unsigned int hi = (c0 + 1 < CINC) ? lt[c0 + 1][px] : 0;
        pk[kk] = lo | (hi << 16);
    }
    unsigned short* dst = cT + (((size_t)(b*HH + y))*WW + x0 + px)*CPAD + cg*32;
#pragma unroll
    for (int u = 0; u < 4; ++u)
        *(uint4*)(dst + u*8) = make_uint4(pk[u*4], pk[u*4+1], pk[u*4+2], pk[u*4+3]);
}

// ---------- fused layer: gate (dilated 3x3 + cond 1x1, tanh*sig) + res/skip 1x1 ----------
// block = 4 waves; tile 256(m, permuted) x 64(px). Coalesced epilogue via LDS transpose.
__global__ __launch_bounds__(256) void layer_fused(
        const unsigned short* __restrict__ hin, unsigned short* __restrict__ hout,
        const unsigned short* __restrict__ zrow, const unsigned short* __restrict__ cT,
        const unsigned short* __restrict__ gw, const float* __restrict__ gbias,
        const unsigned short* __restrict__ rw, const float* __restrict__ rbias,
        float* __restrict__ hf32, float* __restrict__ outskip,
        int layer, int dh, int dw, int first) {
    __shared__ char sbuf[3 * 16384];            // staging x3; buf2 = sact; [0..34816) reused as sres

    const int tid = threadIdx.x, lane = tid & 63, w = tid >> 6;
    const int lrow = lane & 15, lk = lane >> 4;

    // XCD-aware swizzle (bijective: 2048 blocks, 8 XCDs): same-XCD blocks get
    // contiguous x-tiles of the same (b,y) rows -> tap reads L2-local.
    const int lin = blockIdx.x + 64*(blockIdx.y + 16*blockIdx.z);
    const int logical = (lin & 7)*256 + (lin >> 3);
    const int x0 = (logical & 63) * 64;
    const int y  = (logical >> 6) & 15;
    const int b  = logical >> 10;

    f32x4 acc[4][4];
#pragma unroll
    for (int mf = 0; mf < 4; ++mf)
#pragma unroll
        for (int nf = 0; nf < 4; ++nf) acc[mf][nf] = (f32x4){0.f, 0.f, 0.f, 0.f};

    const unsigned short* rowb[3];
#pragma unroll
    for (int kh = 0; kh < 3; ++kh) {
        int yin = y - (2 - kh)*dh;
        rowb[kh] = (yin >= 0) ? hin + ((size_t)(b*HH + yin))*WWP*CCH : zrow;
    }
    const char* cb = (const char*)(cT + (((size_t)(b*HH + y))*WW + x0)*CPAD);

    auto stage = [&](char* dst, const char* src) {
#pragma unroll
        for (int s = 0; s < 4; ++s) {
            unsigned o = (unsigned)(w*4 + s)*1024 + (unsigned)lane*16;
            unsigned g = o ^ (((o >> 8) & 7) << 4);
            gl_lds16(src + g, dst + (w*4 + s)*1024);
        }
    };
    auto stage_t = [&](int t) {
        const char* src;
        if (t == 9) src = cb;
        else {
            int kh = t / 3, kw = t - kh*3;
            src = (const char*)(rowb[kh] + (size_t)(x0 + (kw - 1)*dw + PADW)*CCH);
        }
        stage(sbuf + (t % 3)*16384, src);
    };
    auto dsread = [&](const char* bb, int q, v8s (&bv)[4]) {
#pragma unroll
        for (int nf = 0; nf < 4; ++nf) {
            int px = nf*16 + lrow;
            int o = px*256 + ((q*64 + lk*16) ^ ((lrow & 7) << 4));
            bv[nf] = *(const v8s*)(bb + o);
        }
    };

    // ---- K-loop: 10 uniform 128-ch steps, counted-vmcnt pipeline (proven R6) ----
    stage_t(0);
    stage_t(1);
#pragma unroll
    for (int t = 0; t < NT; ++t) {
        const unsigned short* gq = gw + (((size_t)(layer*NT + t)*4*16) + w*4)*512 + lane*8;
        v8s av[4][4];
#pragma unroll
        for (int q = 0; q < 4; ++q)
#pragma unroll
            for (int mf = 0; mf < 4; ++mf)
                av[q][mf] = *(const v8s*)(gq + q*8192 + mf*512);
        if (t == 0) asm volatile("s_waitcnt vmcnt(20)" ::: "memory");
        else        asm volatile("s_waitcnt vmcnt(32)" ::: "memory");
        __builtin_amdgcn_sched_barrier(0);
        __builtin_amdgcn_s_barrier();
        __builtin_amdgcn_sched_barrier(0);
        if (t + 2 < NT) stage_t(t + 2);
        const char* bb = sbuf + (t % 3)*16384;
        v8s bv[4];
#pragma unroll
        for (int q = 0; q < 4; ++q) {
            dsread(bb, q, bv);
#pragma unroll
            for (int mf = 0; mf < 4; ++mf)
#pragma unroll
                for (int nf = 0; nf < 4; ++nf)
                    acc[mf][nf] = __builtin_amdgcn_mfma_f32_16x16x32_bf16(av[q][mf], bv[nf], acc[mf][nf], 0, 0, 0);
        }
    }

    // ---- gated activation -> sact LDS (buf2, XOR-swizzled) ----
    char* sact = sbuf + 2*16384;
    const float* gb = gbias + layer*256;
#pragma unroll
    for (int mf = 0; mf < 4; ++mf) {
        int m0 = w*64 + mf*16 + lk*4;
        int c0 = m0 >> 1;                     // even
        float bF0 = gb[m0], bG0 = gb[m0+1], bF1 = gb[m0+2], bG1 = gb[m0+3];
#pragma unroll
        for (int nf = 0; nf < 4; ++nf) {
            int px = nf*16 + lrow;
            float o0 = tanhf(acc[mf][nf][0] + bF0) * sigm(acc[mf][nf][1] + bG0);
            float o1 = tanhf(acc[mf][nf][2] + bF1) * sigm(acc[mf][nf][3] + bG1);
            unsigned int pk = (unsigned int)f2bf(o0) | ((unsigned int)f2bf(o1) << 16);
            int byte = px*256 + c0*2;
            byte ^= (px & 7) << 4;
            *(unsigned int*)(sact + byte) = pk;
        }
    }
    __syncthreads();

    // ---- res/skip 1x1 GEMM from sact (M=256 interleaved) ----
    f32x4 racc[4][4];
#pragma unroll
    for (int mf = 0; mf < 4; ++mf)
#pragma unroll
        for (int nf = 0; nf < 4; ++nf) racc[mf][nf] = (f32x4){0.f, 0.f, 0.f, 0.f};

    const unsigned short* rwl = rw + (((size_t)layer*4*16) + w*4)*512 + lane*8;
#pragma unroll
    for (int q = 0; q < 4; ++q) {
        v8s av[4], bv[4];
#pragma unroll
        for (int mf = 0; mf < 4; ++mf) av[mf] = *(const v8s*)(rwl + (size_t)(q*16 + mf)*512);
        dsread(sact, q, bv);
#pragma unroll
        for (int mf = 0; mf < 4; ++mf)
#pragma unroll
            for (int nf = 0; nf < 4; ++nf)
                racc[mf][nf] = __builtin_amdgcn_mfma_f32_16x16x32_bf16(av[mf], bv[nf], racc[mf][nf], 0, 0, 0);
    }
    __syncthreads();                          // all sact reads done before sres overwrite

    // per-thread c-base for transpose: racc rows m0..m0+3 -> res c0,c0+1 (e0,e2), skip c0,c0+1 (e1,e3)
    float* sresf = (float*)sbuf;              // f32 [128][PADF], 34.0 KB
    const int cp = tid >> 4, xg = tid & 15;
    const int pxl = tid & 63, cg = tid >> 6;

    if (layer < NL - 1) {
        // ---- res half: transpose -> sres ----
#pragma unroll
        for (int mf = 0; mf < 4; ++mf) {
            int c0 = w*32 + mf*8 + lk*2;
#pragma unroll
            for (int nf = 0; nf < 4; ++nf) {
                int px = nf*16 + lrow;
                sresf[(c0    )*PADF + px] = racc[mf][nf][0];
                sresf[(c0 + 1)*PADF + px] = racc[mf][nf][2];
            }
        }
        __syncthreads();
        // ---- coalesced fp32 h RMW (float4 streams); h_new back into sres ----
#pragma unroll
        for (int it = 0; it < 8; ++it) {
            int cc = it*16 + cp;
            float4 r = *(float4*)(sresf + cc*PADF + xg*4);
            size_t p = (((size_t)(b*CCH + cc))*HH + y)*WW + x0 + xg*4;
            float4 h = *(const float4*)(hf32 + p);
            float bb2 = rbias[layer*256 + 2*cc];
            h.x += r.x + bb2; h.y += r.y + bb2; h.z += r.z + bb2; h.w += r.w + bb2;
            *(float4*)(hf32 + p) = h;
            *(float4*)(sresf + cc*PADF + xg*4) = h;
        }
        __syncthreads();
        // ---- bf16 shadow: pack h_new [px][c] -> hout ----
        {
            unsigned int pk3[16];
#pragma unroll
            for (int j = 0; j < 16; ++j) {
                float lo = sresf[(cg*32 + 2*j    )*PADF + pxl];
                float hi = sresf[(cg*32 + 2*j + 1)*PADF + pxl];
                pk3[j] = (unsigned int)f2bf(lo) | ((unsigned int)f2bf(hi) << 16);
            }
            unsigned short* hrow = hout + (((size_t)(b*HH + y))*WWP + x0 + pxl + PADW)*CCH + cg*32;
#pragma unroll
            for (int u = 0; u < 4; ++u)
                *(uint4*)(hrow + u*8) = make_uint4(pk3[u*4], pk3[u*4+1], pk3[u*4+2], pk3[u*4+3]);
        }
        __syncthreads();                      // pack reads done before skip-half overwrite
    }

    // ---- skip half: transpose -> sres ----
#pragma unroll
    for (int mf = 0; mf < 4; ++mf) {
        int c0 = w*32 + mf*8 + lk*2;
#pragma unroll
        for (int nf = 0; nf < 4; ++nf) {
            int px = nf*16 + lrow;
            sresf[(c0    )*PADF + px] = racc[mf][nf][1];
            sresf[(c0 + 1)*PADF + px] = racc[mf][nf][3];
        }
    }
    __syncthreads();
    // ---- coalesced skip(d_out) =/+= (float4 streams) ----
#pragma unroll
    for (int it = 0; it < 8; ++it) {
        int cc = it*16 + cp;
        float4 s = *(float4*)(sresf + cc*PADF + xg*4);
        float bb2 = rbias[layer*256 + 2*cc + 1];
        s.x += bb2; s.y += bb2; s.z += bb2; s.w += bb2;
        size_t p = (((size_t)(b*CCH + cc))*HH + y)*WW + x0 + xg*4;
        if (first) {
            *(float4*)(outskip + p) = s;
        } else {
            float4 o = *(const float4*)(outskip + p);
            o.x += s.x; o.y += s.y; o.z += s.z; o.w += s.w;
            *(float4*)(outskip + p) = o;
        }
    }
}

extern "C" void kernel_launch(void* const* d_in, const int* in_sizes, int n_in,
                              void* d_out, int out_size, void* d_ws, size_t ws_size,
                              hipStream_t stream) {
    const float* x       = (const float*)d_in[0];
    const float* c       = (const float*)d_in[1];
    const float* front_w = (const float*)d_in[2];
    const float* front_b = (const float*)d_in[3];
    const float* fg_w    = (const float*)d_in[4];
    const float* fg_b    = (const float*)d_in[5];
    const float* fgc_w   = (const float*)d_in[6];
    const float* fgc_b   = (const float*)d_in[7];
    const float* rs_w    = (const float*)d_in[8];
    const float* rs_b    = (const float*)d_in[9];

    char* ws = (char*)d_ws;
    float* hf32   = (float*)ws;                     ws += (size_t)HF32_N * 4;
    unsigned short* hbf0 = (unsigned short*)ws;     ws += (size_t)HBF_N * 2;
    unsigned short* hbf1 = (unsigned short*)ws;     ws += (size_t)HBF_N * 2;
    unsigned short* zrow = (unsigned short*)ws;     ws += (size_t)ZROW_N * 2;
    unsigned short* cT   = (unsigned short*)ws;     ws += (size_t)CT_N * 2;
    unsigned short* gw   = (unsigned short*)ws;     ws += (size_t)GW_N * 2;
    unsigned short* rwq  = (unsigned short*)ws;     ws += (size_t)RW_N * 2;
    float* gbias  = (float*)ws;                     ws += (size_t)NL * 256 * 4;
    float* rbias  = (float*)ws;

    float* outp = (float*)d_out;

    prep_weights<<<2048, 256, 0, stream>>>(fg_w, fgc_w, rs_w, fg_b, fgc_b, rs_b,
                                           gw, rwq, gbias, rbias);
    front_kernel<<<2048, 256, 0, stream>>>(x, front_w, front_b, hf32, hbf0, hbf1, zrow);
    cond_transpose<<<dim3(64, 16, 2), 256, 0, stream>>>(c, cT);

    static const int DILH[NL] = {1, 2, 4, 8, 1, 2, 4, 8};
    static const int DILW[NL] = {1, 2, 4, 8, 16, 32, 64, 128};

    for (int i = 0; i < NL; ++i) {
        const unsigned short* hin = (i & 1) ? hbf1 : hbf0;
        unsigned short*       hout= (i & 1) ? hbf0 : hbf1;
        layer_fused<<<dim3(64, 16, 2), 256, 0, stream>>>(hin, hout, zrow, cT, gw, gbias,
                                                         rwq, rbias, hf32, outp,
                                                         i, DILH[i], DILW[i], i == 0 ? 1 : 0);
    }
}